// Round 9
// baseline (210.321 us; speedup 1.0000x reference)
//
#include <hip/hip_runtime.h>

typedef unsigned short u16;
typedef unsigned int   u32;
typedef float   f32x4   __attribute__((ext_vector_type(4)));
typedef float   f32x16  __attribute__((ext_vector_type(16)));
typedef __bf16  bf16x8  __attribute__((ext_vector_type(8)));
typedef u16     u16x8   __attribute__((ext_vector_type(8)));
typedef u16     u16x4   __attribute__((ext_vector_type(4)));
typedef u32     u32x4   __attribute__((ext_vector_type(4)));

#define EMBED 1024
#define SEQ   2048
#define NH    16
#define HD    64

// ---- workspace layout (bytes) ----
#define WS_WT  0u          // 4x Wt bf16 [N=1024][K=1024]
#define WS_X   (8u<<20)    // Xq,Xk,Xv bf16 [4096][1024]; ctx reuses Xq
#define WS_QH  (32u<<20)   // Qh bf16 [B,H,S,D], pre-scaled by 0.125*log2(e)
#define WS_KH  (40u<<20)   // Kh bf16 [B,H,S,D]
#define WS_VT  (48u<<20)   // Vs bf16 [B,H,D,S'] with key bits2<->3 swapped
#define WS_CTX WS_X

__device__ __forceinline__ u16 f2bf(float f) {
  unsigned u = __builtin_bit_cast(unsigned, f);
  u += 0x7fffu + ((u >> 16) & 1u);          // RNE
  return (u16)(u >> 16);
}

__device__ __forceinline__ u32 cvtpk(float lo, float hi) {
  u32 r;
  asm("v_cvt_pk_bf16_f32 %0, %1, %2" : "=v"(r) : "v"(lo), "v"(hi));
  return r;
}

__device__ __forceinline__ void gl16(const void* g, void* l) {
  __builtin_amdgcn_global_load_lds((__attribute__((address_space(1))) void*)g,
                                   (__attribute__((address_space(3))) void*)l,
                                   16, 0, 0);
}

// ---------------- pass 0a: fp32 -> bf16 ----------------
__global__ __launch_bounds__(256) void cvt_kernel(const float* __restrict__ q,
                                                  const float* __restrict__ k,
                                                  const float* __restrict__ v,
                                                  u16* __restrict__ X) {
  const float* src = blockIdx.z == 0 ? q : blockIdx.z == 1 ? k : v;
  u16* dst = X + (size_t)blockIdx.z * 4194304u;
  size_t i = ((size_t)blockIdx.x * 256 + threadIdx.x) * 8;
  f32x4 a = *(const f32x4*)(src + i);
  f32x4 b = *(const f32x4*)(src + i + 4);
  u16x8 o;
#pragma unroll
  for (int j = 0; j < 4; ++j) { o[j] = f2bf(a[j]); o[4 + j] = f2bf(b[j]); }
  *(u16x8*)(dst + i) = o;
}

// ---------------- pass 0b: W[K,N] fp32 -> Wt[N,K] bf16 ----------------
__global__ __launch_bounds__(256) void wtrans_kernel(const float* __restrict__ Wq,
                                                     const float* __restrict__ Wk,
                                                     const float* __restrict__ Wv,
                                                     const float* __restrict__ Wo,
                                                     u16* __restrict__ T) {
  const float* W = blockIdx.z == 0 ? Wq : blockIdx.z == 1 ? Wk : blockIdx.z == 2 ? Wv : Wo;
  u16* t = T + (size_t)blockIdx.z * 1048576u;
  __shared__ float sm[32][33];
  const int x = threadIdx.x, y = threadIdx.y;
  const int n0 = blockIdx.x * 32, k0 = blockIdx.y * 32;
#pragma unroll
  for (int i = 0; i < 4; ++i) sm[y + 8 * i][x] = W[(size_t)(k0 + y + 8 * i) * EMBED + n0 + x];
  __syncthreads();
#pragma unroll
  for (int i = 0; i < 4; ++i) t[(size_t)(n0 + y + 8 * i) * EMBED + k0 + x] = f2bf(sm[x][y + 8 * i]);
}

// ---------------- GEMM: C[M,N] = A[M,K] @ Wt^T + bias ----------------
// BK=64 (16 K-iterations, 32 MFMA per barrier-pair), 8-chunk XOR involution
// (sc ^ (row&7)) on BOTH the global source and the LDS read (rule #21);
// 2-way residual read conflict (free). XCD swizzle: each XCD gets 4 contiguous
// A-panels (1MB) and shares the 2MB B panel -> fits 4MB per-XCD L2.
template <int MODE>
__global__ __launch_bounds__(256) void gemm128(char* __restrict__ ws,
                                               const float* __restrict__ bias0,
                                               const float* __restrict__ bias1,
                                               const float* __restrict__ bias2,
                                               float* __restrict__ out) {
  const int z = (MODE == 0) ? blockIdx.z : 0;
  const u16* A  = (MODE == 0) ? (const u16*)(ws + WS_X) + (size_t)z * 4194304u
                              : (const u16*)(ws + WS_CTX);
  const u16* Bt = (const u16*)(ws + WS_WT) + (size_t)((MODE == 0) ? z : 3) * 1048576u;
  const float* bias = (MODE == 0) ? (z == 0 ? bias0 : z == 1 ? bias1 : bias2) : bias0;

  __shared__ u16 lA[128 * 64];
  __shared__ u16 lB[128 * 64];

  const int tid = threadIdx.x, l = tid & 63, w = tid >> 6, g = l >> 4, li = l & 15;

  // XCD-aware swizzle of the 8x32 tile grid (bijective: 256 = 8 XCD * 32)
  const int id = blockIdx.y * 8 + blockIdx.x;
  const int swz = (id & 7) * 32 + (id >> 3);
  const int m0 = (swz >> 3) * 128, n0 = (swz & 7) * 128;

  const int wr = (w >> 1) * 64, wc = (w & 1) * 64;
  const int sr = tid >> 3;      // staging row base 0..31
  const int sc = tid & 7;       // staging 16B-chunk 0..7

  f32x4 acc[4][4] = {};

  for (int kt = 0; kt < 16; ++kt) {
    const int k0 = kt * 64;
#pragma unroll
    for (int rr = 0; rr < 4; ++rr) {
      const int row = rr * 32 + sr;
      const int gsrc = (sc ^ (row & 7)) * 8;
      gl16(A + (size_t)(m0 + row) * 1024 + k0 + gsrc, &lA[row * 64 + sc * 8]);
    }
#pragma unroll
    for (int rr = 0; rr < 4; ++rr) {
      const int row = rr * 32 + sr;
      const int gsrc = (sc ^ (row & 7)) * 8;
      gl16(Bt + (size_t)(n0 + row) * 1024 + k0 + gsrc, &lB[row * 64 + sc * 8]);
    }
    __syncthreads();

    bf16x8 af[4][2], bfr[4][2];
#pragma unroll
    for (int mf = 0; mf < 4; ++mf) {
      const int r = wr + mf * 16 + li;
#pragma unroll
      for (int ks = 0; ks < 2; ++ks)
        af[mf][ks] = __builtin_bit_cast(bf16x8,
            *(const u16x8*)&lA[r * 64 + ((ks * 4 + g) ^ (r & 7)) * 8]);
    }
#pragma unroll
    for (int nf = 0; nf < 4; ++nf) {
      const int r = wc + nf * 16 + li;
#pragma unroll
      for (int ks = 0; ks < 2; ++ks)
        bfr[nf][ks] = __builtin_bit_cast(bf16x8,
            *(const u16x8*)&lB[r * 64 + ((ks * 4 + g) ^ (r & 7)) * 8]);
    }
#pragma unroll
    for (int mf = 0; mf < 4; ++mf)
#pragma unroll
      for (int nf = 0; nf < 4; ++nf) {
        acc[mf][nf] = __builtin_amdgcn_mfma_f32_16x16x32_bf16(af[mf][0], bfr[nf][0], acc[mf][nf], 0, 0, 0);
        acc[mf][nf] = __builtin_amdgcn_mfma_f32_16x16x32_bf16(af[mf][1], bfr[nf][1], acc[mf][nf], 0, 0, 0);
      }
    __syncthreads();
  }

  u16* Qh = (u16*)(ws + WS_QH);
  u16* Kh = (u16*)(ws + WS_KH);
  u16* Vt = (u16*)(ws + WS_VT);
#pragma unroll
  for (int mf = 0; mf < 4; ++mf)
#pragma unroll
    for (int nf = 0; nf < 4; ++nf)
#pragma unroll
      for (int r4 = 0; r4 < 4; ++r4) {
        const int row = m0 + wr + mf * 16 + g * 4 + r4;
        const int col = n0 + wc + nf * 16 + li;
        float v = acc[mf][nf][r4] + bias[col];
        if (MODE == 1) {
          out[(size_t)row * 1024 + col] = v;
        } else {
          const int bb = row >> 11, s = row & 2047, hh = col >> 6, d = col & 63;
          if (z == 0)      Qh[((size_t)(bb * 16 + hh) * SEQ + s) * HD + d] = f2bf(v * 0.1803368801f); // 0.125*log2(e)
          else if (z == 1) Kh[((size_t)(bb * 16 + hh) * SEQ + s) * HD + d] = f2bf(v);
          else {
            const int ssw = (s & ~12) | ((s & 4) << 1) | ((s & 8) >> 1);   // key bits2<->3 swap
            Vt[((size_t)(bb * 16 + hh) * HD + d) * SEQ + ssw] = f2bf(v);
          }
        }
      }
}

// ---------------- pass 2: flash attention, swapped-operand in-register softmax ----------------
// Byte-identical to the round-7 passing kernel EXCEPT s_setprio(1)/(0) wrapped
// around the two MFMA clusters (T5; no addressing/layout change).
__global__ __launch_bounds__(64) void attn_kernel(char* __restrict__ ws) {
  const u16* Qh = (const u16*)(ws + WS_QH);
  const u16* Kh = (const u16*)(ws + WS_KH);
  const u16* Vs = (const u16*)(ws + WS_VT);
  u16* ctx = (u16*)(ws + WS_CTX);

  const int l = threadIdx.x, l31 = l & 31, hi = l >> 5;

  // bijective XCD swizzle: 2048 blocks = 8 * 256; 4 heads' K/V per XCD (~2MB, L2-fits)
  const int id = blockIdx.y * 64 + blockIdx.x;
  const int sw = (id & 7) * 256 + (id >> 3);
  const int bh = sw >> 6, qt = sw & 63;

  const u16* Qp = Qh + (size_t)bh * SEQ * HD;
  const u16* Kp = Kh + (size_t)bh * SEQ * HD;
  const u16* Vp = Vs + (size_t)bh * HD * SEQ;
  const int q = qt * 32 + l31;

  bf16x8 qf[4];
#pragma unroll
  for (int kk = 0; kk < 4; ++kk)
    qf[kk] = __builtin_bit_cast(bf16x8, *(const u16x8*)(Qp + (size_t)q * HD + kk * 16 + 8 * hi));

  f32x16 o0 = {}, o1 = {};
  float m = -1e30f, ls = 0.f;

  u16x8 ka[8], kb[8];
#pragma unroll
  for (int g = 0; g < 2; ++g)
#pragma unroll
    for (int kk = 0; kk < 4; ++kk)
      ka[g * 4 + kk] = *(const u16x8*)(Kp + (size_t)(g * 32 + l31) * HD + kk * 16 + 8 * hi);

#define ATTN_BODY(KC, KN, T)                                                             \
  {                                                                                      \
    const int tn = ((T) + 1) & 31;                                                       \
    _Pragma("unroll")                                                                    \
    for (int g = 0; g < 2; ++g)                                                          \
      _Pragma("unroll")                                                                  \
      for (int kk = 0; kk < 4; ++kk)                                                     \
        KN[g * 4 + kk] = *(const u16x8*)(Kp + (size_t)(tn * 64 + g * 32 + l31) * HD +    \
                                         kk * 16 + 8 * hi);                              \
    f32x16 s0 = {}, s1 = {};                                                             \
    __builtin_amdgcn_s_setprio(1);                                                       \
    _Pragma("unroll")                                                                    \
    for (int kk = 0; kk < 4; ++kk)                                                       \
      s0 = __builtin_amdgcn_mfma_f32_32x32x16_bf16(                                      \
          __builtin_bit_cast(bf16x8, KC[kk]), qf[kk], s0, 0, 0, 0);                      \
    _Pragma("unroll")                                                                    \
    for (int kk = 0; kk < 4; ++kk)                                                       \
      s1 = __builtin_amdgcn_mfma_f32_32x32x16_bf16(                                      \
          __builtin_bit_cast(bf16x8, KC[4 + kk]), qf[kk], s1, 0, 0, 0);                  \
    __builtin_amdgcn_s_setprio(0);                                                       \
    u16x8 vf[2][2][2]; /* [g32][dtile][kk16] */                                          \
    _Pragma("unroll")                                                                    \
    for (int g = 0; g < 2; ++g)                                                          \
      _Pragma("unroll")                                                                  \
      for (int dt = 0; dt < 2; ++dt)                                                     \
        _Pragma("unroll")                                                                \
        for (int kk = 0; kk < 2; ++kk)                                                   \
          vf[g][dt][kk] = *(const u16x8*)(Vp + (size_t)(dt * 32 + l31) * SEQ +           \
                                          (T) * 64 + g * 32 + kk * 16 + 8 * hi);         \
    float pm[4] = {-1e30f, -1e30f, -1e30f, -1e30f};                                      \
    _Pragma("unroll")                                                                    \
    for (int r = 0; r < 16; ++r) {                                                       \
      pm[r & 3] = fmaxf(pm[r & 3], s0[r]);                                               \
      pm[r & 3] = fmaxf(pm[r & 3], s1[r]);                                               \
    }                                                                                    \
    float pmax = fmaxf(fmaxf(pm[0], pm[1]), fmaxf(pm[2], pm[3]));                        \
    pmax = fmaxf(pmax, __shfl_xor(pmax, 32));                                            \
    if (__any(pmax > m + 8.0f)) {                                                        \
      const float mn = fmaxf(m, pmax);                                                   \
      const float esc = __builtin_amdgcn_exp2f(m - mn);                                  \
      m = mn;                                                                            \
      ls *= esc;                                                                         \
      _Pragma("unroll")                                                                  \
      for (int r = 0; r < 16; ++r) { o0[r] *= esc; o1[r] *= esc; }                       \
    }                                                                                    \
    float p0[16], p1[16], sr[4] = {0.f, 0.f, 0.f, 0.f};                                  \
    _Pragma("unroll")                                                                    \
    for (int r = 0; r < 16; ++r) {                                                       \
      p0[r] = __builtin_amdgcn_exp2f(s0[r] - m);                                         \
      p1[r] = __builtin_amdgcn_exp2f(s1[r] - m);                                         \
      sr[r & 3] += p0[r] + p1[r];                                                        \
    }                                                                                    \
    float rs = (sr[0] + sr[1]) + (sr[2] + sr[3]);                                        \
    rs += __shfl_xor(rs, 32);                                                            \
    ls += rs;                                                                            \
    u32 pw[16];                                                                          \
    _Pragma("unroll")                                                                    \
    for (int t2 = 0; t2 < 8; ++t2) {                                                     \
      pw[t2] = cvtpk(p0[2 * t2], p0[2 * t2 + 1]);                                        \
      pw[8 + t2] = cvtpk(p1[2 * t2], p1[2 * t2 + 1]);                                    \
    }                                                                                    \
    __builtin_amdgcn_s_setprio(1);                                                       \
    _Pragma("unroll")                                                                    \
    for (int g = 0; g < 2; ++g)                                                          \
      _Pragma("unroll")                                                                  \
      for (int kk = 0; kk < 2; ++kk) {                                                   \
        u32x4 wv = {pw[g * 8 + kk * 4 + 0], pw[g * 8 + kk * 4 + 1],                      \
                    pw[g * 8 + kk * 4 + 2], pw[g * 8 + kk * 4 + 3]};                     \
        bf16x8 pf = __builtin_bit_cast(bf16x8, wv);                                      \
        o0 = __builtin_amdgcn_mfma_f32_32x32x16_bf16(                                    \
            __builtin_bit_cast(bf16x8, vf[g][0][kk]), pf, o0, 0, 0, 0);                  \
        o1 = __builtin_amdgcn_mfma_f32_32x32x16_bf16(                                    \
            __builtin_bit_cast(bf16x8, vf[g][1][kk]), pf, o1, 0, 0, 0);                  \
      }                                                                                  \
    __builtin_amdgcn_s_setprio(0);                                                       \
  }

  for (int tt = 0; tt < 16; ++tt) {
    ATTN_BODY(ka, kb, 2 * tt);
    ATTN_BODY(kb, ka, 2 * tt + 1);
  }
#undef ATTN_BODY

  const int bb = bh >> 4, hh = bh & 15;
  const float rl = 1.0f / ls;
  u16* cp = ctx + ((size_t)bb * SEQ + q) * EMBED + hh * 64;
#pragma unroll
  for (int rr = 0; rr < 4; ++rr) {
    u16x4 ov0, ov1;
#pragma unroll
    for (int j = 0; j < 4; ++j) {
      ov0[j] = f2bf(o0[rr * 4 + j] * rl);
      ov1[j] = f2bf(o1[rr * 4 + j] * rl);
    }
    *(u16x4*)(cp + rr * 8 + hi * 4) = ov0;
    *(u16x4*)(cp + 32 + rr * 8 + hi * 4) = ov1;
  }
}

extern "C" void kernel_launch(void* const* d_in, const int* in_sizes, int n_in,
                              void* d_out, int out_size, void* d_ws, size_t ws_size,
                              hipStream_t stream) {
  const float* q   = (const float*)d_in[0];
  const float* kin = (const float*)d_in[1];
  const float* val = (const float*)d_in[2];
  const float* Wq  = (const float*)d_in[3];
  const float* bq  = (const float*)d_in[4];
  const float* Wk  = (const float*)d_in[5];
  const float* bk  = (const float*)d_in[6];
  const float* Wv  = (const float*)d_in[7];
  const float* bv  = (const float*)d_in[8];
  const float* Wo  = (const float*)d_in[9];
  const float* bo  = (const float*)d_in[10];
  char* ws = (char*)d_ws;
  float* out = (float*)d_out;

  cvt_kernel<<<dim3(2048, 1, 3), 256, 0, stream>>>(q, kin, val, (u16*)(ws + WS_X));
  wtrans_kernel<<<dim3(32, 32, 4), dim3(32, 8), 0, stream>>>(Wq, Wk, Wv, Wo, (u16*)(ws + WS_WT));
  gemm128<0><<<dim3(8, 32, 3), 256, 0, stream>>>(ws, bq, bk, bv, nullptr);
  attn_kernel<<<dim3(64, 32), 64, 0, stream>>>(ws);
  gemm128<1><<<dim3(8, 32, 1), 256, 0, stream>>>(ws, bo, nullptr, nullptr, out);
}

// Round 10
// 173.148 us; speedup vs baseline: 1.2147x; 1.2147x over previous
//
#include <hip/hip_runtime.h>

typedef unsigned short u16;
typedef unsigned int   u32;
typedef float   f32x4   __attribute__((ext_vector_type(4)));
typedef float   f32x16  __attribute__((ext_vector_type(16)));
typedef __bf16  bf16x8  __attribute__((ext_vector_type(8)));
typedef u16     u16x8   __attribute__((ext_vector_type(8)));
typedef u16     u16x4   __attribute__((ext_vector_type(4)));
typedef u32     u32x4   __attribute__((ext_vector_type(4)));

#define EMBED 1024
#define SEQ   2048
#define NH    16
#define HD    64

// ---- workspace layout (bytes) ----
#define WS_WT  0u          // 4x Wt bf16 [N=1024][K=1024]
#define WS_X   (8u<<20)    // Xq,Xk,Xv bf16 [4096][1024]; ctx reuses Xq
#define WS_QH  (32u<<20)   // Qh bf16 [B,H,S,D], pre-scaled by 0.125*log2(e)
#define WS_KH  (40u<<20)   // Kh bf16 [B,H,S,D]
#define WS_VT  (48u<<20)   // Vs bf16 [B,H,D,S'] with key bits2<->3 swapped
#define WS_CTX WS_X
// fragment-native K, written by repackK_kernel (after gemm<0>) into the
// then-dead Xk region. Slot c*512 + l*8 + j == the element attn lane l
// loads for K-chunk c (c = t*8 + g*4 + kk).
#define WS_KF  (16u<<20)

__device__ __forceinline__ u16 f2bf(float f) {
  unsigned u = __builtin_bit_cast(unsigned, f);
  u += 0x7fffu + ((u >> 16) & 1u);          // RNE
  return (u16)(u >> 16);
}

__device__ __forceinline__ u32 cvtpk(float lo, float hi) {
  u32 r;
  asm("v_cvt_pk_bf16_f32 %0, %1, %2" : "=v"(r) : "v"(lo), "v"(hi));
  return r;
}

__device__ __forceinline__ void gl16(const void* g, void* l) {
  __builtin_amdgcn_global_load_lds((__attribute__((address_space(1))) void*)g,
                                   (__attribute__((address_space(3))) void*)l,
                                   16, 0, 0);
}

// ---------------- pass 0a: fp32 -> bf16 ----------------
__global__ __launch_bounds__(256) void cvt_kernel(const float* __restrict__ q,
                                                  const float* __restrict__ k,
                                                  const float* __restrict__ v,
                                                  u16* __restrict__ X) {
  const float* src = blockIdx.z == 0 ? q : blockIdx.z == 1 ? k : v;
  u16* dst = X + (size_t)blockIdx.z * 4194304u;
  size_t i = ((size_t)blockIdx.x * 256 + threadIdx.x) * 8;
  f32x4 a = *(const f32x4*)(src + i);
  f32x4 b = *(const f32x4*)(src + i + 4);
  u16x8 o;
#pragma unroll
  for (int j = 0; j < 4; ++j) { o[j] = f2bf(a[j]); o[4 + j] = f2bf(b[j]); }
  *(u16x8*)(dst + i) = o;
}

// ---------------- pass 0b: W[K,N] fp32 -> Wt[N,K] bf16 ----------------
__global__ __launch_bounds__(256) void wtrans_kernel(const float* __restrict__ Wq,
                                                     const float* __restrict__ Wk,
                                                     const float* __restrict__ Wv,
                                                     const float* __restrict__ Wo,
                                                     u16* __restrict__ T) {
  const float* W = blockIdx.z == 0 ? Wq : blockIdx.z == 1 ? Wk : blockIdx.z == 2 ? Wv : Wo;
  u16* t = T + (size_t)blockIdx.z * 1048576u;
  __shared__ float sm[32][33];
  const int x = threadIdx.x, y = threadIdx.y;
  const int n0 = blockIdx.x * 32, k0 = blockIdx.y * 32;
#pragma unroll
  for (int i = 0; i < 4; ++i) sm[y + 8 * i][x] = W[(size_t)(k0 + y + 8 * i) * EMBED + n0 + x];
  __syncthreads();
#pragma unroll
  for (int i = 0; i < 4; ++i) t[(size_t)(n0 + y + 8 * i) * EMBED + k0 + x] = f2bf(sm[x][y + 8 * i]);
}

// ---------------- GEMM: C[M,N] = A[M,K] @ Wt^T + bias (round-9 version) ----------------
template <int MODE>
__global__ __launch_bounds__(256) void gemm128(char* __restrict__ ws,
                                               const float* __restrict__ bias0,
                                               const float* __restrict__ bias1,
                                               const float* __restrict__ bias2,
                                               float* __restrict__ out) {
  const int z = (MODE == 0) ? blockIdx.z : 0;
  const u16* A  = (MODE == 0) ? (const u16*)(ws + WS_X) + (size_t)z * 4194304u
                              : (const u16*)(ws + WS_CTX);
  const u16* Bt = (const u16*)(ws + WS_WT) + (size_t)((MODE == 0) ? z : 3) * 1048576u;
  const float* bias = (MODE == 0) ? (z == 0 ? bias0 : z == 1 ? bias1 : bias2) : bias0;

  __shared__ u16 lA[128 * 64];
  __shared__ u16 lB[128 * 64];

  const int tid = threadIdx.x, l = tid & 63, w = tid >> 6, g = l >> 4, li = l & 15;

  const int id = blockIdx.y * 8 + blockIdx.x;
  const int swz = (id & 7) * 32 + (id >> 3);
  const int m0 = (swz >> 3) * 128, n0 = (swz & 7) * 128;

  const int wr = (w >> 1) * 64, wc = (w & 1) * 64;
  const int sr = tid >> 3;
  const int sc = tid & 7;

  f32x4 acc[4][4] = {};

  for (int kt = 0; kt < 16; ++kt) {
    const int k0 = kt * 64;
#pragma unroll
    for (int rr = 0; rr < 4; ++rr) {
      const int row = rr * 32 + sr;
      const int gsrc = (sc ^ (row & 7)) * 8;
      gl16(A + (size_t)(m0 + row) * 1024 + k0 + gsrc, &lA[row * 64 + sc * 8]);
    }
#pragma unroll
    for (int rr = 0; rr < 4; ++rr) {
      const int row = rr * 32 + sr;
      const int gsrc = (sc ^ (row & 7)) * 8;
      gl16(Bt + (size_t)(n0 + row) * 1024 + k0 + gsrc, &lB[row * 64 + sc * 8]);
    }
    __syncthreads();

    bf16x8 af[4][2], bfr[4][2];
#pragma unroll
    for (int mf = 0; mf < 4; ++mf) {
      const int r = wr + mf * 16 + li;
#pragma unroll
      for (int ks = 0; ks < 2; ++ks)
        af[mf][ks] = __builtin_bit_cast(bf16x8,
            *(const u16x8*)&lA[r * 64 + ((ks * 4 + g) ^ (r & 7)) * 8]);
    }
#pragma unroll
    for (int nf = 0; nf < 4; ++nf) {
      const int r = wc + nf * 16 + li;
#pragma unroll
      for (int ks = 0; ks < 2; ++ks)
        bfr[nf][ks] = __builtin_bit_cast(bf16x8,
            *(const u16x8*)&lB[r * 64 + ((ks * 4 + g) ^ (r & 7)) * 8]);
    }
#pragma unroll
    for (int mf = 0; mf < 4; ++mf)
#pragma unroll
      for (int nf = 0; nf < 4; ++nf) {
        acc[mf][nf] = __builtin_amdgcn_mfma_f32_16x16x32_bf16(af[mf][0], bfr[nf][0], acc[mf][nf], 0, 0, 0);
        acc[mf][nf] = __builtin_amdgcn_mfma_f32_16x16x32_bf16(af[mf][1], bfr[nf][1], acc[mf][nf], 0, 0, 0);
      }
    __syncthreads();
  }

  u16* Qh = (u16*)(ws + WS_QH);
  u16* Kh = (u16*)(ws + WS_KH);
  u16* Vt = (u16*)(ws + WS_VT);
#pragma unroll
  for (int mf = 0; mf < 4; ++mf)
#pragma unroll
    for (int nf = 0; nf < 4; ++nf)
#pragma unroll
      for (int r4 = 0; r4 < 4; ++r4) {
        const int row = m0 + wr + mf * 16 + g * 4 + r4;
        const int col = n0 + wc + nf * 16 + li;
        float v = acc[mf][nf][r4] + bias[col];
        if (MODE == 1) {
          out[(size_t)row * 1024 + col] = v;
        } else {
          const int bb = row >> 11, s = row & 2047, hh = col >> 6, d = col & 63;
          if (z == 0)      Qh[((size_t)(bb * 16 + hh) * SEQ + s) * HD + d] = f2bf(v * 0.1803368801f); // 0.125*log2(e)
          else if (z == 1) Kh[((size_t)(bb * 16 + hh) * SEQ + s) * HD + d] = f2bf(v);
          else {
            const int ssw = (s & ~12) | ((s & 4) << 1) | ((s & 8) >> 1);   // key bits2<->3 swap
            Vt[((size_t)(bb * 16 + hh) * HD + d) * SEQ + ssw] = f2bf(v);
          }
        }
      }
}

// ---------------- pass 1b: repack K only into fragment-native layout ----------------
// Bijective permutation. dst[c*512 + l*8 + j] = Kh[t*64 + g*32 + l31][kk*16 + 8*hi + j]
// for c = t*8 + g*4 + kk, l = hi*32 + l31 — exactly the element attn lane l loads
// for K-chunk c. Full coverage of the 8MB Kf region (dead Xk).
__global__ __launch_bounds__(256) void repackK_kernel(char* __restrict__ ws) {
  const int slot = blockIdx.x * 256 + threadIdx.x;   // [0, 16384)
  const int bh = blockIdx.y;
  const int l = slot & 63, c = slot >> 6;
  const int l31 = l & 31, hi = l >> 5;
  const int t = c >> 3, rem = c & 7;
  const u16* src = (const u16*)(ws + WS_KH) + (size_t)bh * SEQ * HD;
  u16* dst = (u16*)(ws + WS_KF) + (size_t)bh * 131072u;
  const int s = t * 64 + (rem >> 2) * 32 + l31;
  const int col = (rem & 3) * 16 + 8 * hi;
  *(u16x8*)(dst + (size_t)slot * 8) = *(const u16x8*)(src + (size_t)s * HD + col);
}

// ---------------- pass 2: flash attention ----------------
// Byte-identical to round 9 EXCEPT the two K fragment load expressions,
// which now read the fragment-native Kf buffer (coalesced 1KB wave-loads).
// V / Q / softmax / output untouched.
__global__ __launch_bounds__(64) void attn_kernel(char* __restrict__ ws) {
  const u16* Qh = (const u16*)(ws + WS_QH);
  const u16* KF = (const u16*)(ws + WS_KF);
  const u16* Vs = (const u16*)(ws + WS_VT);
  u16* ctx = (u16*)(ws + WS_CTX);

  const int l = threadIdx.x, l31 = l & 31, hi = l >> 5;

  // bijective XCD swizzle: 2048 blocks = 8 * 256; 4 heads' K/V per XCD (~2MB, L2-fits)
  const int id = blockIdx.y * 64 + blockIdx.x;
  const int sw = (id & 7) * 256 + (id >> 3);
  const int bh = sw >> 6, qt = sw & 63;

  const u16* Qp = Qh + (size_t)bh * SEQ * HD;
  const u16* Kp = KF + (size_t)bh * 131072u;
  const u16* Vp = Vs + (size_t)bh * HD * SEQ;
  const int q = qt * 32 + l31;

  bf16x8 qf[4];
#pragma unroll
  for (int kk = 0; kk < 4; ++kk)
    qf[kk] = __builtin_bit_cast(bf16x8, *(const u16x8*)(Qp + (size_t)q * HD + kk * 16 + 8 * hi));

  f32x16 o0 = {}, o1 = {};
  float m = -1e30f, ls = 0.f;

  u16x8 ka[8], kb[8];
#pragma unroll
  for (int g = 0; g < 2; ++g)
#pragma unroll
    for (int kk = 0; kk < 4; ++kk)
      ka[g * 4 + kk] = *(const u16x8*)(Kp + (g * 4 + kk) * 512 + l * 8);

#define ATTN_BODY(KC, KN, T)                                                             \
  {                                                                                      \
    const int tn = ((T) + 1) & 31;                                                       \
    _Pragma("unroll")                                                                    \
    for (int g = 0; g < 2; ++g)                                                          \
      _Pragma("unroll")                                                                  \
      for (int kk = 0; kk < 4; ++kk)                                                     \
        KN[g * 4 + kk] = *(const u16x8*)(Kp + tn * 4096 + (g * 4 + kk) * 512 + l * 8);   \
    f32x16 s0 = {}, s1 = {};                                                             \
    __builtin_amdgcn_s_setprio(1);                                                       \
    _Pragma("unroll")                                                                    \
    for (int kk = 0; kk < 4; ++kk)                                                       \
      s0 = __builtin_amdgcn_mfma_f32_32x32x16_bf16(                                      \
          __builtin_bit_cast(bf16x8, KC[kk]), qf[kk], s0, 0, 0, 0);                      \
    _Pragma("unroll")                                                                    \
    for (int kk = 0; kk < 4; ++kk)                                                       \
      s1 = __builtin_amdgcn_mfma_f32_32x32x16_bf16(                                      \
          __builtin_bit_cast(bf16x8, KC[4 + kk]), qf[kk], s1, 0, 0, 0);                  \
    __builtin_amdgcn_s_setprio(0);                                                       \
    u16x8 vf[2][2][2]; /* [g32][dtile][kk16] */                                          \
    _Pragma("unroll")                                                                    \
    for (int g = 0; g < 2; ++g)                                                          \
      _Pragma("unroll")                                                                  \
      for (int dt = 0; dt < 2; ++dt)                                                     \
        _Pragma("unroll")                                                                \
        for (int kk = 0; kk < 2; ++kk)                                                   \
          vf[g][dt][kk] = *(const u16x8*)(Vp + (size_t)(dt * 32 + l31) * SEQ +           \
                                          (T) * 64 + g * 32 + kk * 16 + 8 * hi);         \
    float pm[4] = {-1e30f, -1e30f, -1e30f, -1e30f};                                      \
    _Pragma("unroll")                                                                    \
    for (int r = 0; r < 16; ++r) {                                                       \
      pm[r & 3] = fmaxf(pm[r & 3], s0[r]);                                               \
      pm[r & 3] = fmaxf(pm[r & 3], s1[r]);                                               \
    }                                                                                    \
    float pmax = fmaxf(fmaxf(pm[0], pm[1]), fmaxf(pm[2], pm[3]));                        \
    pmax = fmaxf(pmax, __shfl_xor(pmax, 32));                                            \
    if (__any(pmax > m + 8.0f)) {                                                        \
      const float mn = fmaxf(m, pmax);                                                   \
      const float esc = __builtin_amdgcn_exp2f(m - mn);                                  \
      m = mn;                                                                            \
      ls *= esc;                                                                         \
      _Pragma("unroll")                                                                  \
      for (int r = 0; r < 16; ++r) { o0[r] *= esc; o1[r] *= esc; }                       \
    }                                                                                    \
    float p0[16], p1[16], sr[4] = {0.f, 0.f, 0.f, 0.f};                                  \
    _Pragma("unroll")                                                                    \
    for (int r = 0; r < 16; ++r) {                                                       \
      p0[r] = __builtin_amdgcn_exp2f(s0[r] - m);                                         \
      p1[r] = __builtin_amdgcn_exp2f(s1[r] - m);                                         \
      sr[r & 3] += p0[r] + p1[r];                                                        \
    }                                                                                    \
    float rs = (sr[0] + sr[1]) + (sr[2] + sr[3]);                                        \
    rs += __shfl_xor(rs, 32);                                                            \
    ls += rs;                                                                            \
    u32 pw[16];                                                                          \
    _Pragma("unroll")                                                                    \
    for (int t2 = 0; t2 < 8; ++t2) {                                                     \
      pw[t2] = cvtpk(p0[2 * t2], p0[2 * t2 + 1]);                                        \
      pw[8 + t2] = cvtpk(p1[2 * t2], p1[2 * t2 + 1]);                                    \
    }                                                                                    \
    __builtin_amdgcn_s_setprio(1);                                                       \
    _Pragma("unroll")                                                                    \
    for (int g = 0; g < 2; ++g)                                                          \
      _Pragma("unroll")                                                                  \
      for (int kk = 0; kk < 2; ++kk) {                                                   \
        u32x4 wv = {pw[g * 8 + kk * 4 + 0], pw[g * 8 + kk * 4 + 1],                      \
                    pw[g * 8 + kk * 4 + 2], pw[g * 8 + kk * 4 + 3]};                     \
        bf16x8 pf = __builtin_bit_cast(bf16x8, wv);                                      \
        o0 = __builtin_amdgcn_mfma_f32_32x32x16_bf16(                                    \
            __builtin_bit_cast(bf16x8, vf[g][0][kk]), pf, o0, 0, 0, 0);                  \
        o1 = __builtin_amdgcn_mfma_f32_32x32x16_bf16(                                    \
            __builtin_bit_cast(bf16x8, vf[g][1][kk]), pf, o1, 0, 0, 0);                  \
      }                                                                                  \
    __builtin_amdgcn_s_setprio(0);                                                       \
  }

  for (int tt = 0; tt < 16; ++tt) {
    ATTN_BODY(ka, kb, 2 * tt);
    ATTN_BODY(kb, ka, 2 * tt + 1);
  }
#undef ATTN_BODY

  const int bb = bh >> 4, hh = bh & 15;
  const float rl = 1.0f / ls;
  u16* cp = ctx + ((size_t)bb * SEQ + q) * EMBED + hh * 64;
#pragma unroll
  for (int rr = 0; rr < 4; ++rr) {
    u16x4 ov0, ov1;
#pragma unroll
    for (int j = 0; j < 4; ++j) {
      ov0[j] = f2bf(o0[rr * 4 + j] * rl);
      ov1[j] = f2bf(o1[rr * 4 + j] * rl);
    }
    *(u16x4*)(cp + rr * 8 + hi * 4) = ov0;
    *(u16x4*)(cp + 32 + rr * 8 + hi * 4) = ov1;
  }
}

extern "C" void kernel_launch(void* const* d_in, const int* in_sizes, int n_in,
                              void* d_out, int out_size, void* d_ws, size_t ws_size,
                              hipStream_t stream) {
  const float* q   = (const float*)d_in[0];
  const float* kin = (const float*)d_in[1];
  const float* val = (const float*)d_in[2];
  const float* Wq  = (const float*)d_in[3];
  const float* bq  = (const float*)d_in[4];
  const float* Wk  = (const float*)d_in[5];
  const float* bk  = (const float*)d_in[6];
  const float* Wv  = (const float*)d_in[7];
  const float* bv  = (const float*)d_in[8];
  const float* Wo  = (const float*)d_in[9];
  const float* bo  = (const float*)d_in[10];
  char* ws = (char*)d_ws;
  float* out = (float*)d_out;

  cvt_kernel<<<dim3(2048, 1, 3), 256, 0, stream>>>(q, kin, val, (u16*)(ws + WS_X));
  wtrans_kernel<<<dim3(32, 32, 4), dim3(32, 8), 0, stream>>>(Wq, Wk, Wv, Wo, (u16*)(ws + WS_WT));
  gemm128<0><<<dim3(8, 32, 3), 256, 0, stream>>>(ws, bq, bk, bv, nullptr);
  repackK_kernel<<<dim3(64, 32), 256, 0, stream>>>(ws);
  attn_kernel<<<dim3(64, 32), 64, 0, stream>>>(ws);
  gemm128<1><<<dim3(8, 32, 1), 256, 0, stream>>>(ws, bo, nullptr, nullptr, out);
}

// Round 11
// 157.955 us; speedup vs baseline: 1.3315x; 1.0962x over previous
//
#include <hip/hip_runtime.h>

typedef unsigned short u16;
typedef unsigned int   u32;
typedef float   f32x4   __attribute__((ext_vector_type(4)));
typedef float   f32x16  __attribute__((ext_vector_type(16)));
typedef __bf16  bf16x8  __attribute__((ext_vector_type(8)));
typedef u16     u16x8   __attribute__((ext_vector_type(8)));
typedef u16     u16x4   __attribute__((ext_vector_type(4)));
typedef u32     u32x4   __attribute__((ext_vector_type(4)));

#define EMBED 1024
#define SEQ   2048
#define NH    16
#define HD    64

// ---- workspace layout (bytes) ----
#define WS_WT  0u          // 4x Wt bf16 [N=1024][K=1024]
#define WS_X   (8u<<20)    // Xq,Xk,Xv bf16 [4096][1024]; ctx reuses Xq
#define WS_QH  (32u<<20)   // Qh bf16 [B,H,S,D], pre-scaled by 0.125*log2(e)
#define WS_KH  (40u<<20)   // Kh bf16 [B,H,S,D]
#define WS_VT  (48u<<20)   // Vs bf16 [B,H,D,S'] with key bits2<->3 swapped
#define WS_CTX WS_X
// fragment-native K/V, written by repackK/repackV (after gemm<0>) into the
// then-dead Xk/Xv regions. Slot c*512 + l*8 + j == the element attn lane l
// loads for chunk c (K: c = t*8+g*4+kk; V: c = t*8+dt*4+g*2+kk).
#define WS_KF  (16u<<20)
#define WS_VF  (24u<<20)

__device__ __forceinline__ u16 f2bf(float f) {
  unsigned u = __builtin_bit_cast(unsigned, f);
  u += 0x7fffu + ((u >> 16) & 1u);          // RNE
  return (u16)(u >> 16);
}

__device__ __forceinline__ u32 cvtpk(float lo, float hi) {
  u32 r;
  asm("v_cvt_pk_bf16_f32 %0, %1, %2" : "=v"(r) : "v"(lo), "v"(hi));
  return r;
}

__device__ __forceinline__ void gl16(const void* g, void* l) {
  __builtin_amdgcn_global_load_lds((__attribute__((address_space(1))) void*)g,
                                   (__attribute__((address_space(3))) void*)l,
                                   16, 0, 0);
}

// ---------------- pass 0a: fp32 -> bf16 ----------------
__global__ __launch_bounds__(256) void cvt_kernel(const float* __restrict__ q,
                                                  const float* __restrict__ k,
                                                  const float* __restrict__ v,
                                                  u16* __restrict__ X) {
  const float* src = blockIdx.z == 0 ? q : blockIdx.z == 1 ? k : v;
  u16* dst = X + (size_t)blockIdx.z * 4194304u;
  size_t i = ((size_t)blockIdx.x * 256 + threadIdx.x) * 8;
  f32x4 a = *(const f32x4*)(src + i);
  f32x4 b = *(const f32x4*)(src + i + 4);
  u16x8 o;
#pragma unroll
  for (int j = 0; j < 4; ++j) { o[j] = f2bf(a[j]); o[4 + j] = f2bf(b[j]); }
  *(u16x8*)(dst + i) = o;
}

// ---------------- pass 0b: W[K,N] fp32 -> Wt[N,K] bf16 ----------------
__global__ __launch_bounds__(256) void wtrans_kernel(const float* __restrict__ Wq,
                                                     const float* __restrict__ Wk,
                                                     const float* __restrict__ Wv,
                                                     const float* __restrict__ Wo,
                                                     u16* __restrict__ T) {
  const float* W = blockIdx.z == 0 ? Wq : blockIdx.z == 1 ? Wk : blockIdx.z == 2 ? Wv : Wo;
  u16* t = T + (size_t)blockIdx.z * 1048576u;
  __shared__ float sm[32][33];
  const int x = threadIdx.x, y = threadIdx.y;
  const int n0 = blockIdx.x * 32, k0 = blockIdx.y * 32;
#pragma unroll
  for (int i = 0; i < 4; ++i) sm[y + 8 * i][x] = W[(size_t)(k0 + y + 8 * i) * EMBED + n0 + x];
  __syncthreads();
#pragma unroll
  for (int i = 0; i < 4; ++i) t[(size_t)(n0 + y + 8 * i) * EMBED + k0 + x] = f2bf(sm[x][y + 8 * i]);
}

// ---------------- GEMM: C[M,N] = A[M,K] @ Wt^T + bias (round-7 proven version, BK=32) ----------------
template <int MODE>
__global__ __launch_bounds__(256) void gemm128(char* __restrict__ ws,
                                               const float* __restrict__ bias0,
                                               const float* __restrict__ bias1,
                                               const float* __restrict__ bias2,
                                               float* __restrict__ out) {
  const int z = (MODE == 0) ? blockIdx.z : 0;
  const u16* A  = (MODE == 0) ? (const u16*)(ws + WS_X) + (size_t)z * 4194304u
                              : (const u16*)(ws + WS_CTX);
  const u16* Bt = (const u16*)(ws + WS_WT) + (size_t)((MODE == 0) ? z : 3) * 1048576u;
  const float* bias = (MODE == 0) ? (z == 0 ? bias0 : z == 1 ? bias1 : bias2) : bias0;

  __shared__ u16 lA[128 * 32];
  __shared__ u16 lB[128 * 32];

  const int tid = threadIdx.x, l = tid & 63, w = tid >> 6, g = l >> 4, li = l & 15;
  const int m0 = blockIdx.y * 128, n0 = blockIdx.x * 128;
  const int wr = (w >> 1) * 64, wc = (w & 1) * 64;
  const int schunk = l & 3;

  f32x4 acc[4][4] = {};

  for (int kt = 0; kt < 32; ++kt) {
    const int k0 = kt * 32;
#pragma unroll
    for (int c = 0; c < 2; ++c) {
      const int ci = w * 2 + c;
      const int row = ci * 16 + (l >> 2);
      const int kk = (schunk ^ (row & 3)) * 8;
      gl16(A + (size_t)(m0 + row) * 1024 + k0 + kk, &lA[ci * 512 + l * 8]);
    }
#pragma unroll
    for (int c = 0; c < 2; ++c) {
      const int ci = w * 2 + c;
      const int row = ci * 16 + (l >> 2);
      const int kk = (schunk ^ (row & 3)) * 8;
      gl16(Bt + (size_t)(n0 + row) * 1024 + k0 + kk, &lB[ci * 512 + l * 8]);
    }
    __syncthreads();

    bf16x8 af[4], bfr[4];
#pragma unroll
    for (int mf = 0; mf < 4; ++mf) {
      const int r = wr + mf * 16 + li;
      af[mf] = __builtin_bit_cast(bf16x8, *(const u16x8*)&lA[r * 32 + (g ^ (r & 3)) * 8]);
    }
#pragma unroll
    for (int nf = 0; nf < 4; ++nf) {
      const int r = wc + nf * 16 + li;
      bfr[nf] = __builtin_bit_cast(bf16x8, *(const u16x8*)&lB[r * 32 + (g ^ (r & 3)) * 8]);
    }
#pragma unroll
    for (int mf = 0; mf < 4; ++mf)
#pragma unroll
      for (int nf = 0; nf < 4; ++nf)
        acc[mf][nf] = __builtin_amdgcn_mfma_f32_16x16x32_bf16(af[mf], bfr[nf], acc[mf][nf], 0, 0, 0);
    __syncthreads();
  }

  u16* Qh = (u16*)(ws + WS_QH);
  u16* Kh = (u16*)(ws + WS_KH);
  u16* Vt = (u16*)(ws + WS_VT);
#pragma unroll
  for (int mf = 0; mf < 4; ++mf)
#pragma unroll
    for (int nf = 0; nf < 4; ++nf)
#pragma unroll
      for (int r4 = 0; r4 < 4; ++r4) {
        const int row = m0 + wr + mf * 16 + g * 4 + r4;
        const int col = n0 + wc + nf * 16 + li;
        float v = acc[mf][nf][r4] + bias[col];
        if (MODE == 1) {
          out[(size_t)row * 1024 + col] = v;
        } else {
          const int bb = row >> 11, s = row & 2047, hh = col >> 6, d = col & 63;
          if (z == 0)      Qh[((size_t)(bb * 16 + hh) * SEQ + s) * HD + d] = f2bf(v * 0.1803368801f); // 0.125*log2(e)
          else if (z == 1) Kh[((size_t)(bb * 16 + hh) * SEQ + s) * HD + d] = f2bf(v);
          else {
            const int ssw = (s & ~12) | ((s & 4) << 1) | ((s & 8) >> 1);   // key bits2<->3 swap
            Vt[((size_t)(bb * 16 + hh) * HD + d) * SEQ + ssw] = f2bf(v);
          }
        }
      }
}

// ---------------- pass 1b: repack K into fragment-native layout (round-10 proven) ----------------
__global__ __launch_bounds__(256) void repackK_kernel(char* __restrict__ ws) {
  const int slot = blockIdx.x * 256 + threadIdx.x;   // [0, 16384)
  const int bh = blockIdx.y;
  const int l = slot & 63, c = slot >> 6;
  const int l31 = l & 31, hi = l >> 5;
  const int t = c >> 3, rem = c & 7;
  const u16* src = (const u16*)(ws + WS_KH) + (size_t)bh * SEQ * HD;
  u16* dst = (u16*)(ws + WS_KF) + (size_t)bh * 131072u;
  const int s = t * 64 + (rem >> 2) * 32 + l31;
  const int col = (rem & 3) * 16 + 8 * hi;
  *(u16x8*)(dst + (size_t)slot * 8) = *(const u16x8*)(src + (size_t)s * HD + col);
}

// ---------------- pass 1c: repack V into fragment-native layout (V-analog of repackK) ----------------
// dst[c*512 + l*8 + j] = Vs[dt*32 + l31][t*64 + g*32 + kk*16 + 8*hi + j]
// for c = t*8 + dt*4 + g*2 + kk — exactly the element attn lane l loads for V-chunk c.
__global__ __launch_bounds__(256) void repackV_kernel(char* __restrict__ ws) {
  const int slot = blockIdx.x * 256 + threadIdx.x;   // [0, 16384)
  const int bh = blockIdx.y;
  const int l = slot & 63, c = slot >> 6;
  const int l31 = l & 31, hi = l >> 5;
  const int t = c >> 3, rem = c & 7;
  const u16* src = (const u16*)(ws + WS_VT) + (size_t)bh * HD * SEQ;
  u16* dst = (u16*)(ws + WS_VF) + (size_t)bh * 131072u;
  const int d = (rem >> 2) * 32 + l31;
  const int col = t * 64 + ((rem >> 1) & 1) * 32 + (rem & 1) * 16 + 8 * hi;
  *(u16x8*)(dst + (size_t)slot * 8) = *(const u16x8*)(src + (size_t)d * SEQ + col);
}

// ---------------- pass 2: flash attention ----------------
// Byte-identical to round 10 EXCEPT the V fragment loads, which now read the
// fragment-native Vf buffer (coalesced 1KB wave-loads, same template as K).
__global__ __launch_bounds__(64) void attn_kernel(char* __restrict__ ws) {
  const u16* Qh = (const u16*)(ws + WS_QH);
  const u16* KF = (const u16*)(ws + WS_KF);
  const u16* VF = (const u16*)(ws + WS_VF);
  u16* ctx = (u16*)(ws + WS_CTX);

  const int l = threadIdx.x, l31 = l & 31, hi = l >> 5;

  // bijective XCD swizzle: 2048 blocks = 8 * 256; 4 heads' K/V per XCD (~2MB, L2-fits)
  const int id = blockIdx.y * 64 + blockIdx.x;
  const int sw = (id & 7) * 256 + (id >> 3);
  const int bh = sw >> 6, qt = sw & 63;

  const u16* Qp = Qh + (size_t)bh * SEQ * HD;
  const u16* Kp = KF + (size_t)bh * 131072u;
  const u16* Vp = VF + (size_t)bh * 131072u;
  const int q = qt * 32 + l31;

  bf16x8 qf[4];
#pragma unroll
  for (int kk = 0; kk < 4; ++kk)
    qf[kk] = __builtin_bit_cast(bf16x8, *(const u16x8*)(Qp + (size_t)q * HD + kk * 16 + 8 * hi));

  f32x16 o0 = {}, o1 = {};
  float m = -1e30f, ls = 0.f;

  u16x8 ka[8], kb[8];
#pragma unroll
  for (int g = 0; g < 2; ++g)
#pragma unroll
    for (int kk = 0; kk < 4; ++kk)
      ka[g * 4 + kk] = *(const u16x8*)(Kp + (g * 4 + kk) * 512 + l * 8);

#define ATTN_BODY(KC, KN, T)                                                             \
  {                                                                                      \
    const int tn = ((T) + 1) & 31;                                                       \
    _Pragma("unroll")                                                                    \
    for (int g = 0; g < 2; ++g)                                                          \
      _Pragma("unroll")                                                                  \
      for (int kk = 0; kk < 4; ++kk)                                                     \
        KN[g * 4 + kk] = *(const u16x8*)(Kp + tn * 4096 + (g * 4 + kk) * 512 + l * 8);   \
    f32x16 s0 = {}, s1 = {};                                                             \
    __builtin_amdgcn_s_setprio(1);                                                       \
    _Pragma("unroll")                                                                    \
    for (int kk = 0; kk < 4; ++kk)                                                       \
      s0 = __builtin_amdgcn_mfma_f32_32x32x16_bf16(                                      \
          __builtin_bit_cast(bf16x8, KC[kk]), qf[kk], s0, 0, 0, 0);                      \
    _Pragma("unroll")                                                                    \
    for (int kk = 0; kk < 4; ++kk)                                                       \
      s1 = __builtin_amdgcn_mfma_f32_32x32x16_bf16(                                      \
          __builtin_bit_cast(bf16x8, KC[4 + kk]), qf[kk], s1, 0, 0, 0);                  \
    __builtin_amdgcn_s_setprio(0);                                                       \
    u16x8 vf[2][2][2]; /* [g32][dtile][kk16] */                                          \
    _Pragma("unroll")                                                                    \
    for (int g = 0; g < 2; ++g)                                                          \
      _Pragma("unroll")                                                                  \
      for (int dt = 0; dt < 2; ++dt)                                                     \
        _Pragma("unroll")                                                                \
        for (int kk = 0; kk < 2; ++kk)                                                   \
          vf[g][dt][kk] = *(const u16x8*)(Vp + (T) * 4096 +                              \
                                          (dt * 4 + g * 2 + kk) * 512 + l * 8);          \
    float pm[4] = {-1e30f, -1e30f, -1e30f, -1e30f};                                      \
    _Pragma("unroll")                                                                    \
    for (int r = 0; r < 16; ++r) {                                                       \
      pm[r & 3] = fmaxf(pm[r & 3], s0[r]);                                               \
      pm[r & 3] = fmaxf(pm[r & 3], s1[r]);                                               \
    }                                                                                    \
    float pmax = fmaxf(fmaxf(pm[0], pm[1]), fmaxf(pm[2], pm[3]));                        \
    pmax = fmaxf(pmax, __shfl_xor(pmax, 32));                                            \
    if (__any(pmax > m + 8.0f)) {                                                        \
      const float mn = fmaxf(m, pmax);                                                   \
      const float esc = __builtin_amdgcn_exp2f(m - mn);                                  \
      m = mn;                                                                            \
      ls *= esc;                                                                         \
      _Pragma("unroll")                                                                  \
      for (int r = 0; r < 16; ++r) { o0[r] *= esc; o1[r] *= esc; }                       \
    }                                                                                    \
    float p0[16], p1[16], sr[4] = {0.f, 0.f, 0.f, 0.f};                                  \
    _Pragma("unroll")                                                                    \
    for (int r = 0; r < 16; ++r) {                                                       \
      p0[r] = __builtin_amdgcn_exp2f(s0[r] - m);                                         \
      p1[r] = __builtin_amdgcn_exp2f(s1[r] - m);                                         \
      sr[r & 3] += p0[r] + p1[r];                                                        \
    }                                                                                    \
    float rs = (sr[0] + sr[1]) + (sr[2] + sr[3]);                                        \
    rs += __shfl_xor(rs, 32);                                                            \
    ls += rs;                                                                            \
    u32 pw[16];                                                                          \
    _Pragma("unroll")                                                                    \
    for (int t2 = 0; t2 < 8; ++t2) {                                                     \
      pw[t2] = cvtpk(p0[2 * t2], p0[2 * t2 + 1]);                                        \
      pw[8 + t2] = cvtpk(p1[2 * t2], p1[2 * t2 + 1]);                                    \
    }                                                                                    \
    __builtin_amdgcn_s_setprio(1);                                                       \
    _Pragma("unroll")                                                                    \
    for (int g = 0; g < 2; ++g)                                                          \
      _Pragma("unroll")                                                                  \
      for (int kk = 0; kk < 2; ++kk) {                                                   \
        u32x4 wv = {pw[g * 8 + kk * 4 + 0], pw[g * 8 + kk * 4 + 1],                      \
                    pw[g * 8 + kk * 4 + 2], pw[g * 8 + kk * 4 + 3]};                     \
        bf16x8 pf = __builtin_bit_cast(bf16x8, wv);                                      \
        o0 = __builtin_amdgcn_mfma_f32_32x32x16_bf16(                                    \
            __builtin_bit_cast(bf16x8, vf[g][0][kk]), pf, o0, 0, 0, 0);                  \
        o1 = __builtin_amdgcn_mfma_f32_32x32x16_bf16(                                    \
            __builtin_bit_cast(bf16x8, vf[g][1][kk]), pf, o1, 0, 0, 0);                  \
      }                                                                                  \
    __builtin_amdgcn_s_setprio(0);                                                       \
  }

  for (int tt = 0; tt < 16; ++tt) {
    ATTN_BODY(ka, kb, 2 * tt);
    ATTN_BODY(kb, ka, 2 * tt + 1);
  }
#undef ATTN_BODY

  const int bb = bh >> 4, hh = bh & 15;
  const float rl = 1.0f / ls;
  u16* cp = ctx + ((size_t)bb * SEQ + q) * EMBED + hh * 64;
#pragma unroll
  for (int rr = 0; rr < 4; ++rr) {
    u16x4 ov0, ov1;
#pragma unroll
    for (int j = 0; j < 4; ++j) {
      ov0[j] = f2bf(o0[rr * 4 + j] * rl);
      ov1[j] = f2bf(o1[rr * 4 + j] * rl);
    }
    *(u16x4*)(cp + rr * 8 + hi * 4) = ov0;
    *(u16x4*)(cp + 32 + rr * 8 + hi * 4) = ov1;
  }
}

extern "C" void kernel_launch(void* const* d_in, const int* in_sizes, int n_in,
                              void* d_out, int out_size, void* d_ws, size_t ws_size,
                              hipStream_t stream) {
  const float* q   = (const float*)d_in[0];
  const float* kin = (const float*)d_in[1];
  const float* val = (const float*)d_in[2];
  const float* Wq  = (const float*)d_in[3];
  const float* bq  = (const float*)d_in[4];
  const float* Wk  = (const float*)d_in[5];
  const float* bk  = (const float*)d_in[6];
  const float* Wv  = (const float*)d_in[7];
  const float* bv  = (const float*)d_in[8];
  const float* Wo  = (const float*)d_in[9];
  const float* bo  = (const float*)d_in[10];
  char* ws = (char*)d_ws;
  float* out = (float*)d_out;

  cvt_kernel<<<dim3(2048, 1, 3), 256, 0, stream>>>(q, kin, val, (u16*)(ws + WS_X));
  wtrans_kernel<<<dim3(32, 32, 4), dim3(32, 8), 0, stream>>>(Wq, Wk, Wv, Wo, (u16*)(ws + WS_WT));
  gemm128<0><<<dim3(8, 32, 3), 256, 0, stream>>>(ws, bq, bk, bv, nullptr);
  repackK_kernel<<<dim3(64, 32), 256, 0, stream>>>(ws);
  repackV_kernel<<<dim3(64, 32), 256, 0, stream>>>(ws);
  attn_kernel<<<dim3(64, 32), 64, 0, stream>>>(ws);
  gemm128<1><<<dim3(8, 32, 1), 256, 0, stream>>>(ws, bo, nullptr, nullptr, out);
}

// Round 12
// 156.900 us; speedup vs baseline: 1.3405x; 1.0067x over previous
//
#include <hip/hip_runtime.h>

typedef unsigned short u16;
typedef unsigned int   u32;
typedef float   f32x4   __attribute__((ext_vector_type(4)));
typedef float   f32x16  __attribute__((ext_vector_type(16)));
typedef __bf16  bf16x8  __attribute__((ext_vector_type(8)));
typedef u16     u16x8   __attribute__((ext_vector_type(8)));
typedef u16     u16x4   __attribute__((ext_vector_type(4)));
typedef u32     u32x4   __attribute__((ext_vector_type(4)));

#define EMBED 1024
#define SEQ   2048
#define NH    16
#define HD    64

// ---- workspace layout (bytes) ----
#define WS_WT  0u          // 4x Wt bf16 [N=1024][K=1024]
#define WS_X   (8u<<20)    // Xq,Xk,Xv bf16 [4096][1024]; ctx reuses Xq
#define WS_QH  (32u<<20)   // Qh bf16 [B,H,S,D], pre-scaled by 0.125*log2(e)
#define WS_CTX WS_X
// fragment-native K/V, written DIRECTLY by gemm<0>'s epilogue (fused repack).
// Placed in the 40/48MB regions (old Kh/Vt) — these are write-only during
// gemm<0>, so no overlap with its A-inputs Xk (16-24MB) / Xv (24-32MB).
// Slot c*512 + l*8 + j == the element attn lane l loads for chunk c
// (K: c = t*8+g*4+kk; V: c = t*8+dt*4+g*2+kk). Formulas are the verified
// composition of the round-10/11 repack kernels with the old Kh/Vt layouts.
#define WS_KF  (40u<<20)
#define WS_VF  (48u<<20)

__device__ __forceinline__ u16 f2bf(float f) {
  unsigned u = __builtin_bit_cast(unsigned, f);
  u += 0x7fffu + ((u >> 16) & 1u);          // RNE
  return (u16)(u >> 16);
}

__device__ __forceinline__ u32 cvtpk(float lo, float hi) {
  u32 r;
  asm("v_cvt_pk_bf16_f32 %0, %1, %2" : "=v"(r) : "v"(lo), "v"(hi));
  return r;
}

__device__ __forceinline__ void gl16(const void* g, void* l) {
  __builtin_amdgcn_global_load_lds((__attribute__((address_space(1))) void*)g,
                                   (__attribute__((address_space(3))) void*)l,
                                   16, 0, 0);
}

// ---------------- pass 0a: fp32 -> bf16 ----------------
__global__ __launch_bounds__(256) void cvt_kernel(const float* __restrict__ q,
                                                  const float* __restrict__ k,
                                                  const float* __restrict__ v,
                                                  u16* __restrict__ X) {
  const float* src = blockIdx.z == 0 ? q : blockIdx.z == 1 ? k : v;
  u16* dst = X + (size_t)blockIdx.z * 4194304u;
  size_t i = ((size_t)blockIdx.x * 256 + threadIdx.x) * 8;
  f32x4 a = *(const f32x4*)(src + i);
  f32x4 b = *(const f32x4*)(src + i + 4);
  u16x8 o;
#pragma unroll
  for (int j = 0; j < 4; ++j) { o[j] = f2bf(a[j]); o[4 + j] = f2bf(b[j]); }
  *(u16x8*)(dst + i) = o;
}

// ---------------- pass 0b: W[K,N] fp32 -> Wt[N,K] bf16 ----------------
__global__ __launch_bounds__(256) void wtrans_kernel(const float* __restrict__ Wq,
                                                     const float* __restrict__ Wk,
                                                     const float* __restrict__ Wv,
                                                     const float* __restrict__ Wo,
                                                     u16* __restrict__ T) {
  const float* W = blockIdx.z == 0 ? Wq : blockIdx.z == 1 ? Wk : blockIdx.z == 2 ? Wv : Wo;
  u16* t = T + (size_t)blockIdx.z * 1048576u;
  __shared__ float sm[32][33];
  const int x = threadIdx.x, y = threadIdx.y;
  const int n0 = blockIdx.x * 32, k0 = blockIdx.y * 32;
#pragma unroll
  for (int i = 0; i < 4; ++i) sm[y + 8 * i][x] = W[(size_t)(k0 + y + 8 * i) * EMBED + n0 + x];
  __syncthreads();
#pragma unroll
  for (int i = 0; i < 4; ++i) t[(size_t)(n0 + y + 8 * i) * EMBED + k0 + x] = f2bf(sm[x][y + 8 * i]);
}

// ---------------- GEMM: C[M,N] = A[M,K] @ Wt^T + bias (round-7 proven, BK=32) ----------------
// MODE 0 epilogue scatters DIRECTLY to fragment-native Qh/Kf/Vf (fused repack).
template <int MODE>
__global__ __launch_bounds__(256) void gemm128(char* __restrict__ ws,
                                               const float* __restrict__ bias0,
                                               const float* __restrict__ bias1,
                                               const float* __restrict__ bias2,
                                               float* __restrict__ out) {
  const int z = (MODE == 0) ? blockIdx.z : 0;
  const u16* A  = (MODE == 0) ? (const u16*)(ws + WS_X) + (size_t)z * 4194304u
                              : (const u16*)(ws + WS_CTX);
  const u16* Bt = (const u16*)(ws + WS_WT) + (size_t)((MODE == 0) ? z : 3) * 1048576u;
  const float* bias = (MODE == 0) ? (z == 0 ? bias0 : z == 1 ? bias1 : bias2) : bias0;

  __shared__ u16 lA[128 * 32];
  __shared__ u16 lB[128 * 32];

  const int tid = threadIdx.x, l = tid & 63, w = tid >> 6, g = l >> 4, li = l & 15;
  const int m0 = blockIdx.y * 128, n0 = blockIdx.x * 128;
  const int wr = (w >> 1) * 64, wc = (w & 1) * 64;
  const int schunk = l & 3;

  f32x4 acc[4][4] = {};

  for (int kt = 0; kt < 32; ++kt) {
    const int k0 = kt * 32;
#pragma unroll
    for (int c = 0; c < 2; ++c) {
      const int ci = w * 2 + c;
      const int row = ci * 16 + (l >> 2);
      const int kk = (schunk ^ (row & 3)) * 8;
      gl16(A + (size_t)(m0 + row) * 1024 + k0 + kk, &lA[ci * 512 + l * 8]);
    }
#pragma unroll
    for (int c = 0; c < 2; ++c) {
      const int ci = w * 2 + c;
      const int row = ci * 16 + (l >> 2);
      const int kk = (schunk ^ (row & 3)) * 8;
      gl16(Bt + (size_t)(n0 + row) * 1024 + k0 + kk, &lB[ci * 512 + l * 8]);
    }
    __syncthreads();

    bf16x8 af[4], bfr[4];
#pragma unroll
    for (int mf = 0; mf < 4; ++mf) {
      const int r = wr + mf * 16 + li;
      af[mf] = __builtin_bit_cast(bf16x8, *(const u16x8*)&lA[r * 32 + (g ^ (r & 3)) * 8]);
    }
#pragma unroll
    for (int nf = 0; nf < 4; ++nf) {
      const int r = wc + nf * 16 + li;
      bfr[nf] = __builtin_bit_cast(bf16x8, *(const u16x8*)&lB[r * 32 + (g ^ (r & 3)) * 8]);
    }
#pragma unroll
    for (int mf = 0; mf < 4; ++mf)
#pragma unroll
      for (int nf = 0; nf < 4; ++nf)
        acc[mf][nf] = __builtin_amdgcn_mfma_f32_16x16x32_bf16(af[mf], bfr[nf], acc[mf][nf], 0, 0, 0);
    __syncthreads();
  }

  u16* Qh = (u16*)(ws + WS_QH);
  u16* Kf = (u16*)(ws + WS_KF);
  u16* Vf = (u16*)(ws + WS_VF);
#pragma unroll
  for (int mf = 0; mf < 4; ++mf)
#pragma unroll
    for (int nf = 0; nf < 4; ++nf)
#pragma unroll
      for (int r4 = 0; r4 < 4; ++r4) {
        const int row = m0 + wr + mf * 16 + g * 4 + r4;
        const int col = n0 + wc + nf * 16 + li;
        float v = acc[mf][nf][r4] + bias[col];
        if (MODE == 1) {
          out[(size_t)row * 1024 + col] = v;
        } else {
          const int bb = row >> 11, s = row & 2047, hh = col >> 6, d = col & 63;
          const size_t fb = (size_t)(bb * 16 + hh) * 131072u;
          if (z == 0) {
            Qh[((size_t)(bb * 16 + hh) * SEQ + s) * HD + d] = f2bf(v * 0.1803368801f); // 0.125*log2(e)
          } else if (z == 1) {
            // Kf[t*4096 + g*2048 + kk*512 + hi*256 + l31*8 + j] = K[s][d]
            // (verified composition of round-10 repackK with the Kh layout)
            Kf[fb + (s >> 6) * 4096 + ((s >> 5) & 1) * 2048 + (d >> 4) * 512 +
               ((d >> 3) & 1) * 256 + (s & 31) * 8 + (d & 7)] = f2bf(v);
          } else {
            // Vf[t*4096 + dt*2048 + g*1024 + kk*512 + hi*256 + l31*8 + j] with
            // 8*hi+j = swap23(s&15) (verified composition of round-11 repackV)
            const int k16 = s & 15;
            const int ks = (k16 & 3) | ((k16 & 4) << 1) | ((k16 & 8) >> 1);  // swap bits2<->3
            Vf[fb + (s >> 6) * 4096 + (d >> 5) * 2048 + ((s >> 5) & 1) * 1024 +
               ((s >> 4) & 1) * 512 + (ks >> 3) * 256 + (d & 31) * 8 + (ks & 7)] = f2bf(v);
          }
        }
      }
}

// ---------------- pass 2: flash attention ----------------
// Byte-identical to round 11 (only the WS_KF/WS_VF macro values moved to the
// 40/48MB regions now written directly by gemm<0>'s fused epilogue).
__global__ __launch_bounds__(64) void attn_kernel(char* __restrict__ ws) {
  const u16* Qh = (const u16*)(ws + WS_QH);
  const u16* KF = (const u16*)(ws + WS_KF);
  const u16* VF = (const u16*)(ws + WS_VF);
  u16* ctx = (u16*)(ws + WS_CTX);

  const int l = threadIdx.x, l31 = l & 31, hi = l >> 5;

  // bijective XCD swizzle: 2048 blocks = 8 * 256; 4 heads' K/V per XCD (~2MB, L2-fits)
  const int id = blockIdx.y * 64 + blockIdx.x;
  const int sw = (id & 7) * 256 + (id >> 3);
  const int bh = sw >> 6, qt = sw & 63;

  const u16* Qp = Qh + (size_t)bh * SEQ * HD;
  const u16* Kp = KF + (size_t)bh * 131072u;
  const u16* Vp = VF + (size_t)bh * 131072u;
  const int q = qt * 32 + l31;

  bf16x8 qf[4];
#pragma unroll
  for (int kk = 0; kk < 4; ++kk)
    qf[kk] = __builtin_bit_cast(bf16x8, *(const u16x8*)(Qp + (size_t)q * HD + kk * 16 + 8 * hi));

  f32x16 o0 = {}, o1 = {};
  float m = -1e30f, ls = 0.f;

  u16x8 ka[8], kb[8];
#pragma unroll
  for (int g = 0; g < 2; ++g)
#pragma unroll
    for (int kk = 0; kk < 4; ++kk)
      ka[g * 4 + kk] = *(const u16x8*)(Kp + (g * 4 + kk) * 512 + l * 8);

#define ATTN_BODY(KC, KN, T)                                                             \
  {                                                                                      \
    const int tn = ((T) + 1) & 31;                                                       \
    _Pragma("unroll")                                                                    \
    for (int g = 0; g < 2; ++g)                                                          \
      _Pragma("unroll")                                                                  \
      for (int kk = 0; kk < 4; ++kk)                                                     \
        KN[g * 4 + kk] = *(const u16x8*)(Kp + tn * 4096 + (g * 4 + kk) * 512 + l * 8);   \
    f32x16 s0 = {}, s1 = {};                                                             \
    __builtin_amdgcn_s_setprio(1);                                                       \
    _Pragma("unroll")                                                                    \
    for (int kk = 0; kk < 4; ++kk)                                                       \
      s0 = __builtin_amdgcn_mfma_f32_32x32x16_bf16(                                      \
          __builtin_bit_cast(bf16x8, KC[kk]), qf[kk], s0, 0, 0, 0);                      \
    _Pragma("unroll")                                                                    \
    for (int kk = 0; kk < 4; ++kk)                                                       \
      s1 = __builtin_amdgcn_mfma_f32_32x32x16_bf16(                                      \
          __builtin_bit_cast(bf16x8, KC[4 + kk]), qf[kk], s1, 0, 0, 0);                  \
    __builtin_amdgcn_s_setprio(0);                                                       \
    u16x8 vf[2][2][2]; /* [g32][dtile][kk16] */                                          \
    _Pragma("unroll")                                                                    \
    for (int g = 0; g < 2; ++g)                                                          \
      _Pragma("unroll")                                                                  \
      for (int dt = 0; dt < 2; ++dt)                                                     \
        _Pragma("unroll")                                                                \
        for (int kk = 0; kk < 2; ++kk)                                                   \
          vf[g][dt][kk] = *(const u16x8*)(Vp + (T) * 4096 +                              \
                                          (dt * 4 + g * 2 + kk) * 512 + l * 8);          \
    float pm[4] = {-1e30f, -1e30f, -1e30f, -1e30f};                                      \
    _Pragma("unroll")                                                                    \
    for (int r = 0; r < 16; ++r) {                                                       \
      pm[r & 3] = fmaxf(pm[r & 3], s0[r]);                                               \
      pm[r & 3] = fmaxf(pm[r & 3], s1[r]);                                               \
    }                                                                                    \
    float pmax = fmaxf(fmaxf(pm[0], pm[1]), fmaxf(pm[2], pm[3]));                        \
    pmax = fmaxf(pmax, __shfl_xor(pmax, 32));                                            \
    if (__any(pmax > m + 8.0f)) {                                                        \
      const float mn = fmaxf(m, pmax);                                                   \
      const float esc = __builtin_amdgcn_exp2f(m - mn);                                  \
      m = mn;                                                                            \
      ls *= esc;                                                                         \
      _Pragma("unroll")                                                                  \
      for (int r = 0; r < 16; ++r) { o0[r] *= esc; o1[r] *= esc; }                       \
    }                                                                                    \
    float p0[16], p1[16], sr[4] = {0.f, 0.f, 0.f, 0.f};                                  \
    _Pragma("unroll")                                                                    \
    for (int r = 0; r < 16; ++r) {                                                       \
      p0[r] = __builtin_amdgcn_exp2f(s0[r] - m);                                         \
      p1[r] = __builtin_amdgcn_exp2f(s1[r] - m);                                         \
      sr[r & 3] += p0[r] + p1[r];                                                        \
    }                                                                                    \
    float rs = (sr[0] + sr[1]) + (sr[2] + sr[3]);                                        \
    rs += __shfl_xor(rs, 32);                                                            \
    ls += rs;                                                                            \
    u32 pw[16];                                                                          \
    _Pragma("unroll")                                                                    \
    for (int t2 = 0; t2 < 8; ++t2) {                                                     \
      pw[t2] = cvtpk(p0[2 * t2], p0[2 * t2 + 1]);                                        \
      pw[8 + t2] = cvtpk(p1[2 * t2], p1[2 * t2 + 1]);                                    \
    }                                                                                    \
    __builtin_amdgcn_s_setprio(1);                                                       \
    _Pragma("unroll")                                                                    \
    for (int g = 0; g < 2; ++g)                                                          \
      _Pragma("unroll")                                                                  \
      for (int kk = 0; kk < 2; ++kk) {                                                   \
        u32x4 wv = {pw[g * 8 + kk * 4 + 0], pw[g * 8 + kk * 4 + 1],                      \
                    pw[g * 8 + kk * 4 + 2], pw[g * 8 + kk * 4 + 3]};                     \
        bf16x8 pf = __builtin_bit_cast(bf16x8, wv);                                      \
        o0 = __builtin_amdgcn_mfma_f32_32x32x16_bf16(                                    \
            __builtin_bit_cast(bf16x8, vf[g][0][kk]), pf, o0, 0, 0, 0);                  \
        o1 = __builtin_amdgcn_mfma_f32_32x32x16_bf16(                                    \
            __builtin_bit_cast(bf16x8, vf[g][1][kk]), pf, o1, 0, 0, 0);                  \
      }                                                                                  \
    __builtin_amdgcn_s_setprio(0);                                                       \
  }

  for (int tt = 0; tt < 16; ++tt) {
    ATTN_BODY(ka, kb, 2 * tt);
    ATTN_BODY(kb, ka, 2 * tt + 1);
  }
#undef ATTN_BODY

  const int bb = bh >> 4, hh = bh & 15;
  const float rl = 1.0f / ls;
  u16* cp = ctx + ((size_t)bb * SEQ + q) * EMBED + hh * 64;
#pragma unroll
  for (int rr = 0; rr < 4; ++rr) {
    u16x4 ov0, ov1;
#pragma unroll
    for (int j = 0; j < 4; ++j) {
      ov0[j] = f2bf(o0[rr * 4 + j] * rl);
      ov1[j] = f2bf(o1[rr * 4 + j] * rl);
    }
    *(u16x4*)(cp + rr * 8 + hi * 4) = ov0;
    *(u16x4*)(cp + 32 + rr * 8 + hi * 4) = ov1;
  }
}

extern "C" void kernel_launch(void* const* d_in, const int* in_sizes, int n_in,
                              void* d_out, int out_size, void* d_ws, size_t ws_size,
                              hipStream_t stream) {
  const float* q   = (const float*)d_in[0];
  const float* kin = (const float*)d_in[1];
  const float* val = (const float*)d_in[2];
  const float* Wq  = (const float*)d_in[3];
  const float* bq  = (const float*)d_in[4];
  const float* Wk  = (const float*)d_in[5];
  const float* bk  = (const float*)d_in[6];
  const float* Wv  = (const float*)d_in[7];
  const float* bv  = (const float*)d_in[8];
  const float* Wo  = (const float*)d_in[9];
  const float* bo  = (const float*)d_in[10];
  char* ws = (char*)d_ws;
  float* out = (float*)d_out;

  cvt_kernel<<<dim3(2048, 1, 3), 256, 0, stream>>>(q, kin, val, (u16*)(ws + WS_X));
  wtrans_kernel<<<dim3(32, 32, 4), dim3(32, 8), 0, stream>>>(Wq, Wk, Wv, Wo, (u16*)(ws + WS_WT));
  gemm128<0><<<dim3(8, 32, 3), 256, 0, stream>>>(ws, bq, bk, bv, nullptr);
  attn_kernel<<<dim3(64, 32), 64, 0, stream>>>(ws);
  gemm128<1><<<dim3(8, 32, 1), 256, 0, stream>>>(ws, bo, nullptr, nullptr, out);
}

// Round 13
// 140.244 us; speedup vs baseline: 1.4997x; 1.1188x over previous
//
#include <hip/hip_runtime.h>

typedef unsigned short u16;
typedef unsigned int   u32;
typedef float   f32x4   __attribute__((ext_vector_type(4)));
typedef float   f32x16  __attribute__((ext_vector_type(16)));
typedef __bf16  bf16x8  __attribute__((ext_vector_type(8)));
typedef u16     u16x8   __attribute__((ext_vector_type(8)));
typedef u16     u16x4   __attribute__((ext_vector_type(4)));
typedef u32     u32x4   __attribute__((ext_vector_type(4)));

#define EMBED 1024
#define SEQ   2048
#define NH    16
#define HD    64

// ---- workspace layout (bytes) ----
#define WS_WT  0u          // 4x Wt bf16 [N=1024][K=1024]
#define WS_X   (8u<<20)    // Xq,Xk,Xv bf16 [4096][1024]; ctx reuses Xq
#define WS_QH  (32u<<20)   // Qh bf16 [B,H,S,D], pre-scaled by 0.125*log2(e)
#define WS_CTX WS_X
// fragment-native K/V, written DIRECTLY by gemm<0>'s epilogue (fused repack).
#define WS_KF  (40u<<20)
#define WS_VF  (48u<<20)

__device__ __forceinline__ u16 f2bf(float f) {
  unsigned u = __builtin_bit_cast(unsigned, f);
  u += 0x7fffu + ((u >> 16) & 1u);          // RNE
  return (u16)(u >> 16);
}

__device__ __forceinline__ u32 cvtpk(float lo, float hi) {
  u32 r;
  asm("v_cvt_pk_bf16_f32 %0, %1, %2" : "=v"(r) : "v"(lo), "v"(hi));
  return r;
}

__device__ __forceinline__ void gl16(const void* g, void* l) {
  __builtin_amdgcn_global_load_lds((__attribute__((address_space(1))) void*)g,
                                   (__attribute__((address_space(3))) void*)l,
                                   16, 0, 0);
}

// ---------------- pass 0a: fp32 -> bf16 ----------------
__global__ __launch_bounds__(256) void cvt_kernel(const float* __restrict__ q,
                                                  const float* __restrict__ k,
                                                  const float* __restrict__ v,
                                                  u16* __restrict__ X) {
  const float* src = blockIdx.z == 0 ? q : blockIdx.z == 1 ? k : v;
  u16* dst = X + (size_t)blockIdx.z * 4194304u;
  size_t i = ((size_t)blockIdx.x * 256 + threadIdx.x) * 8;
  f32x4 a = *(const f32x4*)(src + i);
  f32x4 b = *(const f32x4*)(src + i + 4);
  u16x8 o;
#pragma unroll
  for (int j = 0; j < 4; ++j) { o[j] = f2bf(a[j]); o[4 + j] = f2bf(b[j]); }
  *(u16x8*)(dst + i) = o;
}

// ---------------- pass 0b: W[K,N] fp32 -> Wt[N,K] bf16 ----------------
__global__ __launch_bounds__(256) void wtrans_kernel(const float* __restrict__ Wq,
                                                     const float* __restrict__ Wk,
                                                     const float* __restrict__ Wv,
                                                     const float* __restrict__ Wo,
                                                     u16* __restrict__ T) {
  const float* W = blockIdx.z == 0 ? Wq : blockIdx.z == 1 ? Wk : blockIdx.z == 2 ? Wv : Wo;
  u16* t = T + (size_t)blockIdx.z * 1048576u;
  __shared__ float sm[32][33];
  const int x = threadIdx.x, y = threadIdx.y;
  const int n0 = blockIdx.x * 32, k0 = blockIdx.y * 32;
#pragma unroll
  for (int i = 0; i < 4; ++i) sm[y + 8 * i][x] = W[(size_t)(k0 + y + 8 * i) * EMBED + n0 + x];
  __syncthreads();
#pragma unroll
  for (int i = 0; i < 4; ++i) t[(size_t)(n0 + y + 8 * i) * EMBED + k0 + x] = f2bf(sm[x][y + 8 * i]);
}

// ---------------- GEMM: C[M,N] = A[M,K] @ Wt^T + bias (round-12 + XCD swizzle) ----------------
// XCD-aware tile remap: linear block id -> XCD = id&7; each XCD now covers
// 4 contiguous m-tiles x all 8 n-tiles (working set 1MB A-strip + 2MB B = 3MB,
// fits the 4MB per-XCD L2; the old mapping streamed all 8MB of A per XCD).
template <int MODE>
__global__ __launch_bounds__(256) void gemm128(char* __restrict__ ws,
                                               const float* __restrict__ bias0,
                                               const float* __restrict__ bias1,
                                               const float* __restrict__ bias2,
                                               float* __restrict__ out) {
  const int z = (MODE == 0) ? blockIdx.z : 0;
  const u16* A  = (MODE == 0) ? (const u16*)(ws + WS_X) + (size_t)z * 4194304u
                              : (const u16*)(ws + WS_CTX);
  const u16* Bt = (const u16*)(ws + WS_WT) + (size_t)((MODE == 0) ? z : 3) * 1048576u;
  const float* bias = (MODE == 0) ? (z == 0 ? bias0 : z == 1 ? bias1 : bias2) : bias0;

  __shared__ u16 lA[128 * 32];
  __shared__ u16 lB[128 * 32];

  const int tid = threadIdx.x, l = tid & 63, w = tid >> 6, g = l >> 4, li = l & 15;

  const int id = blockIdx.y * 8 + blockIdx.x;        // [0,256)
  const int swz = (id & 7) * 32 + (id >> 3);         // bijective; XCD-contiguous
  const int m0 = (swz >> 3) * 128, n0 = (swz & 7) * 128;

  const int wr = (w >> 1) * 64, wc = (w & 1) * 64;
  const int schunk = l & 3;

  f32x4 acc[4][4] = {};

  for (int kt = 0; kt < 32; ++kt) {
    const int k0 = kt * 32;
#pragma unroll
    for (int c = 0; c < 2; ++c) {
      const int ci = w * 2 + c;
      const int row = ci * 16 + (l >> 2);
      const int kk = (schunk ^ (row & 3)) * 8;
      gl16(A + (size_t)(m0 + row) * 1024 + k0 + kk, &lA[ci * 512 + l * 8]);
    }
#pragma unroll
    for (int c = 0; c < 2; ++c) {
      const int ci = w * 2 + c;
      const int row = ci * 16 + (l >> 2);
      const int kk = (schunk ^ (row & 3)) * 8;
      gl16(Bt + (size_t)(n0 + row) * 1024 + k0 + kk, &lB[ci * 512 + l * 8]);
    }
    __syncthreads();

    bf16x8 af[4], bfr[4];
#pragma unroll
    for (int mf = 0; mf < 4; ++mf) {
      const int r = wr + mf * 16 + li;
      af[mf] = __builtin_bit_cast(bf16x8, *(const u16x8*)&lA[r * 32 + (g ^ (r & 3)) * 8]);
    }
#pragma unroll
    for (int nf = 0; nf < 4; ++nf) {
      const int r = wc + nf * 16 + li;
      bfr[nf] = __builtin_bit_cast(bf16x8, *(const u16x8*)&lB[r * 32 + (g ^ (r & 3)) * 8]);
    }
#pragma unroll
    for (int mf = 0; mf < 4; ++mf)
#pragma unroll
      for (int nf = 0; nf < 4; ++nf)
        acc[mf][nf] = __builtin_amdgcn_mfma_f32_16x16x32_bf16(af[mf], bfr[nf], acc[mf][nf], 0, 0, 0);
    __syncthreads();
  }

  u16* Qh = (u16*)(ws + WS_QH);
  u16* Kf = (u16*)(ws + WS_KF);
  u16* Vf = (u16*)(ws + WS_VF);
#pragma unroll
  for (int mf = 0; mf < 4; ++mf)
#pragma unroll
    for (int nf = 0; nf < 4; ++nf)
#pragma unroll
      for (int r4 = 0; r4 < 4; ++r4) {
        const int row = m0 + wr + mf * 16 + g * 4 + r4;
        const int col = n0 + wc + nf * 16 + li;
        float v = acc[mf][nf][r4] + bias[col];
        if (MODE == 1) {
          out[(size_t)row * 1024 + col] = v;
        } else {
          const int bb = row >> 11, s = row & 2047, hh = col >> 6, d = col & 63;
          const size_t fb = (size_t)(bb * 16 + hh) * 131072u;
          if (z == 0) {
            Qh[((size_t)(bb * 16 + hh) * SEQ + s) * HD + d] = f2bf(v * 0.1803368801f); // 0.125*log2(e)
          } else if (z == 1) {
            Kf[fb + (s >> 6) * 4096 + ((s >> 5) & 1) * 2048 + (d >> 4) * 512 +
               ((d >> 3) & 1) * 256 + (s & 31) * 8 + (d & 7)] = f2bf(v);
          } else {
            const int k16 = s & 15;
            const int ks = (k16 & 3) | ((k16 & 4) << 1) | ((k16 & 8) >> 1);  // swap bits2<->3
            Vf[fb + (s >> 6) * 4096 + (d >> 5) * 2048 + ((s >> 5) & 1) * 1024 +
               ((s >> 4) & 1) * 512 + (ks >> 3) * 256 + (d & 31) * 8 + (ks & 7)] = f2bf(v);
          }
        }
      }
}

// ---------------- pass 2: flash attention, split-K 2-wave ----------------
// Round-12-proven body macro VERBATIM (only the prefetch ring is rebased).
// Block = 2 waves sharing one (bh, qt): wave w handles k-tiles [w*16, w*16+16),
// then a standard online-softmax merge through LDS (lane l holds the same
// q-row in both waves, so the merge is lane-aligned). 16 waves/CU (was 8).
__global__ __launch_bounds__(128) void attn_kernel(char* __restrict__ ws) {
  const u16* Qh = (const u16*)(ws + WS_QH);
  const u16* KF = (const u16*)(ws + WS_KF);
  const u16* VF = (const u16*)(ws + WS_VF);
  u16* ctx = (u16*)(ws + WS_CTX);

  const int tid = threadIdx.x, l = tid & 63, wv = tid >> 6, l31 = l & 31, hi = (l >> 5) & 1;

  // bijective XCD swizzle: 2048 blocks = 8 * 256; 4 heads' K/V per XCD (~2MB, L2-fits)
  const int id = blockIdx.y * 64 + blockIdx.x;
  const int sw = (id & 7) * 256 + (id >> 3);
  const int bh = sw >> 6, qt = sw & 63;

  const u16* Qp = Qh + (size_t)bh * SEQ * HD;
  const u16* Kp = KF + (size_t)bh * 131072u;
  const u16* Vp = VF + (size_t)bh * 131072u;
  const int q = qt * 32 + l31;
  const int tb = wv * 16;                 // this wave's k-tile base

  __shared__ float sm_o[64][33];          // wave-1 o (32 floats/lane, pad 33)
  __shared__ float sm_mls[2][64];         // wave-1 m, ls

  bf16x8 qf[4];
#pragma unroll
  for (int kk = 0; kk < 4; ++kk)
    qf[kk] = __builtin_bit_cast(bf16x8, *(const u16x8*)(Qp + (size_t)q * HD + kk * 16 + 8 * hi));

  f32x16 o0 = {}, o1 = {};
  float m = -1e30f, ls = 0.f;

  u16x8 ka[8], kb[8];
#pragma unroll
  for (int g = 0; g < 2; ++g)
#pragma unroll
    for (int kk = 0; kk < 4; ++kk)
      ka[g * 4 + kk] = *(const u16x8*)(Kp + tb * 4096 + (g * 4 + kk) * 512 + l * 8);

#define ATTN_BODY(KC, KN, T)                                                             \
  {                                                                                      \
    const int tn = tb + ((((T) - tb) + 1) & 15);                                         \
    _Pragma("unroll")                                                                    \
    for (int g = 0; g < 2; ++g)                                                          \
      _Pragma("unroll")                                                                  \
      for (int kk = 0; kk < 4; ++kk)                                                     \
        KN[g * 4 + kk] = *(const u16x8*)(Kp + tn * 4096 + (g * 4 + kk) * 512 + l * 8);   \
    f32x16 s0 = {}, s1 = {};                                                             \
    __builtin_amdgcn_s_setprio(1);                                                       \
    _Pragma("unroll")                                                                    \
    for (int kk = 0; kk < 4; ++kk)                                                       \
      s0 = __builtin_amdgcn_mfma_f32_32x32x16_bf16(                                      \
          __builtin_bit_cast(bf16x8, KC[kk]), qf[kk], s0, 0, 0, 0);                      \
    _Pragma("unroll")                                                                    \
    for (int kk = 0; kk < 4; ++kk)                                                       \
      s1 = __builtin_amdgcn_mfma_f32_32x32x16_bf16(                                      \
          __builtin_bit_cast(bf16x8, KC[4 + kk]), qf[kk], s1, 0, 0, 0);                  \
    __builtin_amdgcn_s_setprio(0);                                                       \
    u16x8 vf[2][2][2]; /* [g32][dtile][kk16] */                                          \
    _Pragma("unroll")                                                                    \
    for (int g = 0; g < 2; ++g)                                                          \
      _Pragma("unroll")                                                                  \
      for (int dt = 0; dt < 2; ++dt)                                                     \
        _Pragma("unroll")                                                                \
        for (int kk = 0; kk < 2; ++kk)                                                   \
          vf[g][dt][kk] = *(const u16x8*)(Vp + (T) * 4096 +                              \
                                          (dt * 4 + g * 2 + kk) * 512 + l * 8);          \
    float pm[4] = {-1e30f, -1e30f, -1e30f, -1e30f};                                      \
    _Pragma("unroll")                                                                    \
    for (int r = 0; r < 16; ++r) {                                                       \
      pm[r & 3] = fmaxf(pm[r & 3], s0[r]);                                               \
      pm[r & 3] = fmaxf(pm[r & 3], s1[r]);                                               \
    }                                                                                    \
    float pmax = fmaxf(fmaxf(pm[0], pm[1]), fmaxf(pm[2], pm[3]));                        \
    pmax = fmaxf(pmax, __shfl_xor(pmax, 32));                                            \
    if (__any(pmax > m + 8.0f)) {                                                        \
      const float mn = fmaxf(m, pmax);                                                   \
      const float esc = __builtin_amdgcn_exp2f(m - mn);                                  \
      m = mn;                                                                            \
      ls *= esc;                                                                         \
      _Pragma("unroll")                                                                  \
      for (int r = 0; r < 16; ++r) { o0[r] *= esc; o1[r] *= esc; }                       \
    }                                                                                    \
    float p0[16], p1[16], sr[4] = {0.f, 0.f, 0.f, 0.f};                                  \
    _Pragma("unroll")                                                                    \
    for (int r = 0; r < 16; ++r) {                                                       \
      p0[r] = __builtin_amdgcn_exp2f(s0[r] - m);                                         \
      p1[r] = __builtin_amdgcn_exp2f(s1[r] - m);                                         \
      sr[r & 3] += p0[r] + p1[r];                                                        \
    }                                                                                    \
    float rs = (sr[0] + sr[1]) + (sr[2] + sr[3]);                                        \
    rs += __shfl_xor(rs, 32);                                                            \
    ls += rs;                                                                            \
    u32 pw[16];                                                                          \
    _Pragma("unroll")                                                                    \
    for (int t2 = 0; t2 < 8; ++t2) {                                                     \
      pw[t2] = cvtpk(p0[2 * t2], p0[2 * t2 + 1]);                                        \
      pw[8 + t2] = cvtpk(p1[2 * t2], p1[2 * t2 + 1]);                                    \
    }                                                                                    \
    __builtin_amdgcn_s_setprio(1);                                                       \
    _Pragma("unroll")                                                                    \
    for (int g = 0; g < 2; ++g)                                                          \
      _Pragma("unroll")                                                                  \
      for (int kk = 0; kk < 2; ++kk) {                                                   \
        u32x4 wvv = {pw[g * 8 + kk * 4 + 0], pw[g * 8 + kk * 4 + 1],                     \
                     pw[g * 8 + kk * 4 + 2], pw[g * 8 + kk * 4 + 3]};                    \
        bf16x8 pf = __builtin_bit_cast(bf16x8, wvv);                                     \
        o0 = __builtin_amdgcn_mfma_f32_32x32x16_bf16(                                    \
            __builtin_bit_cast(bf16x8, vf[g][0][kk]), pf, o0, 0, 0, 0);                  \
        o1 = __builtin_amdgcn_mfma_f32_32x32x16_bf16(                                    \
            __builtin_bit_cast(bf16x8, vf[g][1][kk]), pf, o1, 0, 0, 0);                  \
      }                                                                                  \
    __builtin_amdgcn_s_setprio(0);                                                       \
  }

  for (int tt = 0; tt < 8; ++tt) {
    ATTN_BODY(ka, kb, tb + 2 * tt);
    ATTN_BODY(kb, ka, tb + 2 * tt + 1);
  }
#undef ATTN_BODY

  // ---- split-K merge: wave 1 publishes, wave 0 combines and writes ----
  if (wv == 1) {
    sm_mls[0][l] = m;
    sm_mls[1][l] = ls;
#pragma unroll
    for (int j = 0; j < 16; ++j) {
      sm_o[l][j] = o0[j];
      sm_o[l][16 + j] = o1[j];
    }
  }
  __syncthreads();
  if (wv == 0) {
    const float m2 = sm_mls[0][l], ls2 = sm_mls[1][l];
    const float mn = fmaxf(m, m2);
    const float e1 = __builtin_amdgcn_exp2f(m - mn);
    const float e2 = __builtin_amdgcn_exp2f(m2 - mn);
    const float rl = 1.0f / (ls * e1 + ls2 * e2);
    const int bb = bh >> 4, hh = bh & 15;
    u16* cp = ctx + ((size_t)bb * SEQ + q) * EMBED + hh * 64;
#pragma unroll
    for (int rr = 0; rr < 4; ++rr) {
      u16x4 ov0, ov1;
#pragma unroll
      for (int j = 0; j < 4; ++j) {
        const int idx = rr * 4 + j;
        ov0[j] = f2bf((o0[idx] * e1 + sm_o[l][idx] * e2) * rl);
        ov1[j] = f2bf((o1[idx] * e1 + sm_o[l][16 + idx] * e2) * rl);
      }
      *(u16x4*)(cp + rr * 8 + hi * 4) = ov0;
      *(u16x4*)(cp + 32 + rr * 8 + hi * 4) = ov1;
    }
  }
}

extern "C" void kernel_launch(void* const* d_in, const int* in_sizes, int n_in,
                              void* d_out, int out_size, void* d_ws, size_t ws_size,
                              hipStream_t stream) {
  const float* q   = (const float*)d_in[0];
  const float* kin = (const float*)d_in[1];
  const float* val = (const float*)d_in[2];
  const float* Wq  = (const float*)d_in[3];
  const float* bq  = (const float*)d_in[4];
  const float* Wk  = (const float*)d_in[5];
  const float* bk  = (const float*)d_in[6];
  const float* Wv  = (const float*)d_in[7];
  const float* bv  = (const float*)d_in[8];
  const float* Wo  = (const float*)d_in[9];
  const float* bo  = (const float*)d_in[10];
  char* ws = (char*)d_ws;
  float* out = (float*)d_out;

  cvt_kernel<<<dim3(2048, 1, 3), 256, 0, stream>>>(q, kin, val, (u16*)(ws + WS_X));
  wtrans_kernel<<<dim3(32, 32, 4), dim3(32, 8), 0, stream>>>(Wq, Wk, Wv, Wo, (u16*)(ws + WS_WT));
  gemm128<0><<<dim3(8, 32, 3), 256, 0, stream>>>(ws, bq, bk, bv, nullptr);
  attn_kernel<<<dim3(64, 32), 128, 0, stream>>>(ws);
  gemm128<1><<<dim3(8, 32, 1), 256, 0, stream>>>(ws, bo, nullptr, nullptr, out);
}

// Round 14
// 136.852 us; speedup vs baseline: 1.5368x; 1.0248x over previous
//
#include <hip/hip_runtime.h>

typedef unsigned short u16;
typedef unsigned int   u32;
typedef float   f32x4   __attribute__((ext_vector_type(4)));
typedef float   f32x16  __attribute__((ext_vector_type(16)));
typedef __bf16  bf16x8  __attribute__((ext_vector_type(8)));
typedef u16     u16x8   __attribute__((ext_vector_type(8)));
typedef u16     u16x4   __attribute__((ext_vector_type(4)));
typedef u32     u32x4   __attribute__((ext_vector_type(4)));

#define EMBED 1024
#define SEQ   2048
#define NH    16
#define HD    64

// ---- workspace layout (bytes) ----
#define WS_WT  0u          // 4x Wt bf16 [N=1024][K=1024]
#define WS_X   (8u<<20)    // Xq,Xk,Xv bf16 [4096][1024]; ctx reuses Xq
#define WS_QF  (32u<<20)   // fragment-native Q (same formula as Kf, pre-scaled)
#define WS_CTX WS_X
// fragment-native Q/K/V, written DIRECTLY by gemm<0>'s epilogue (fused repack).
// Slot c*512 + l*8 + j == the element attn lane l loads for chunk c
// (Q: c = qt*4+kk; K: c = t*8+g*4+kk; V: c = t*8+dt*4+g*2+kk).
#define WS_KF  (40u<<20)
#define WS_VF  (48u<<20)

__device__ __forceinline__ u16 f2bf(float f) {
  unsigned u = __builtin_bit_cast(unsigned, f);
  u += 0x7fffu + ((u >> 16) & 1u);          // RNE
  return (u16)(u >> 16);
}

__device__ __forceinline__ u32 cvtpk(float lo, float hi) {
  u32 r;
  asm("v_cvt_pk_bf16_f32 %0, %1, %2" : "=v"(r) : "v"(lo), "v"(hi));
  return r;
}

__device__ __forceinline__ void gl16(const void* g, void* l) {
  __builtin_amdgcn_global_load_lds((__attribute__((address_space(1))) void*)g,
                                   (__attribute__((address_space(3))) void*)l,
                                   16, 0, 0);
}

// ---------------- pass 0a: fp32 -> bf16 ----------------
__global__ __launch_bounds__(256) void cvt_kernel(const float* __restrict__ q,
                                                  const float* __restrict__ k,
                                                  const float* __restrict__ v,
                                                  u16* __restrict__ X) {
  const float* src = blockIdx.z == 0 ? q : blockIdx.z == 1 ? k : v;
  u16* dst = X + (size_t)blockIdx.z * 4194304u;
  size_t i = ((size_t)blockIdx.x * 256 + threadIdx.x) * 8;
  f32x4 a = *(const f32x4*)(src + i);
  f32x4 b = *(const f32x4*)(src + i + 4);
  u16x8 o;
#pragma unroll
  for (int j = 0; j < 4; ++j) { o[j] = f2bf(a[j]); o[4 + j] = f2bf(b[j]); }
  *(u16x8*)(dst + i) = o;
}

// ---------------- pass 0b: W[K,N] fp32 -> Wt[N,K] bf16 ----------------
__global__ __launch_bounds__(256) void wtrans_kernel(const float* __restrict__ Wq,
                                                     const float* __restrict__ Wk,
                                                     const float* __restrict__ Wv,
                                                     const float* __restrict__ Wo,
                                                     u16* __restrict__ T) {
  const float* W = blockIdx.z == 0 ? Wq : blockIdx.z == 1 ? Wk : blockIdx.z == 2 ? Wv : Wo;
  u16* t = T + (size_t)blockIdx.z * 1048576u;
  __shared__ float sm[32][33];
  const int x = threadIdx.x, y = threadIdx.y;
  const int n0 = blockIdx.x * 32, k0 = blockIdx.y * 32;
#pragma unroll
  for (int i = 0; i < 4; ++i) sm[y + 8 * i][x] = W[(size_t)(k0 + y + 8 * i) * EMBED + n0 + x];
  __syncthreads();
#pragma unroll
  for (int i = 0; i < 4; ++i) t[(size_t)(n0 + y + 8 * i) * EMBED + k0 + x] = f2bf(sm[x][y + 8 * i]);
}

// ---------------- GEMM: C[M,N] = A[M,K] @ Wt^T + bias (round-13 proven) ----------------
// MODE 0 epilogue scatters DIRECTLY to fragment-native Qf/Kf/Vf (fused repack).
// z==0 now uses the SAME verified formula as z==1 (Q fragments == K fragments).
template <int MODE>
__global__ __launch_bounds__(256) void gemm128(char* __restrict__ ws,
                                               const float* __restrict__ bias0,
                                               const float* __restrict__ bias1,
                                               const float* __restrict__ bias2,
                                               float* __restrict__ out) {
  const int z = (MODE == 0) ? blockIdx.z : 0;
  const u16* A  = (MODE == 0) ? (const u16*)(ws + WS_X) + (size_t)z * 4194304u
                              : (const u16*)(ws + WS_CTX);
  const u16* Bt = (const u16*)(ws + WS_WT) + (size_t)((MODE == 0) ? z : 3) * 1048576u;
  const float* bias = (MODE == 0) ? (z == 0 ? bias0 : z == 1 ? bias1 : bias2) : bias0;

  __shared__ u16 lA[128 * 32];
  __shared__ u16 lB[128 * 32];

  const int tid = threadIdx.x, l = tid & 63, w = tid >> 6, g = l >> 4, li = l & 15;

  const int id = blockIdx.y * 8 + blockIdx.x;        // [0,256)
  const int swz = (id & 7) * 32 + (id >> 3);         // bijective; XCD-contiguous
  const int m0 = (swz >> 3) * 128, n0 = (swz & 7) * 128;

  const int wr = (w >> 1) * 64, wc = (w & 1) * 64;
  const int schunk = l & 3;

  f32x4 acc[4][4] = {};

  for (int kt = 0; kt < 32; ++kt) {
    const int k0 = kt * 32;
#pragma unroll
    for (int c = 0; c < 2; ++c) {
      const int ci = w * 2 + c;
      const int row = ci * 16 + (l >> 2);
      const int kk = (schunk ^ (row & 3)) * 8;
      gl16(A + (size_t)(m0 + row) * 1024 + k0 + kk, &lA[ci * 512 + l * 8]);
    }
#pragma unroll
    for (int c = 0; c < 2; ++c) {
      const int ci = w * 2 + c;
      const int row = ci * 16 + (l >> 2);
      const int kk = (schunk ^ (row & 3)) * 8;
      gl16(Bt + (size_t)(n0 + row) * 1024 + k0 + kk, &lB[ci * 512 + l * 8]);
    }
    __syncthreads();

    bf16x8 af[4], bfr[4];
#pragma unroll
    for (int mf = 0; mf < 4; ++mf) {
      const int r = wr + mf * 16 + li;
      af[mf] = __builtin_bit_cast(bf16x8, *(const u16x8*)&lA[r * 32 + (g ^ (r & 3)) * 8]);
    }
#pragma unroll
    for (int nf = 0; nf < 4; ++nf) {
      const int r = wc + nf * 16 + li;
      bfr[nf] = __builtin_bit_cast(bf16x8, *(const u16x8*)&lB[r * 32 + (g ^ (r & 3)) * 8]);
    }
#pragma unroll
    for (int mf = 0; mf < 4; ++mf)
#pragma unroll
      for (int nf = 0; nf < 4; ++nf)
        acc[mf][nf] = __builtin_amdgcn_mfma_f32_16x16x32_bf16(af[mf], bfr[nf], acc[mf][nf], 0, 0, 0);
    __syncthreads();
  }

  u16* Qf = (u16*)(ws + WS_QF);
  u16* Kf = (u16*)(ws + WS_KF);
  u16* Vf = (u16*)(ws + WS_VF);
#pragma unroll
  for (int mf = 0; mf < 4; ++mf)
#pragma unroll
    for (int nf = 0; nf < 4; ++nf)
#pragma unroll
      for (int r4 = 0; r4 < 4; ++r4) {
        const int row = m0 + wr + mf * 16 + g * 4 + r4;
        const int col = n0 + wc + nf * 16 + li;
        float v = acc[mf][nf][r4] + bias[col];
        if (MODE == 1) {
          out[(size_t)row * 1024 + col] = v;
        } else {
          const int bb = row >> 11, s = row & 2047, hh = col >> 6, d = col & 63;
          const size_t fb = (size_t)(bb * 16 + hh) * 131072u;
          const size_t kfo = fb + (s >> 6) * 4096 + ((s >> 5) & 1) * 2048 + (d >> 4) * 512 +
                             ((d >> 3) & 1) * 256 + (s & 31) * 8 + (d & 7);
          if (z == 0) {
            Qf[kfo] = f2bf(v * 0.1803368801f);   // 0.125*log2(e); Q frags == K frags
          } else if (z == 1) {
            Kf[kfo] = f2bf(v);
          } else {
            const int k16 = s & 15;
            const int ks = (k16 & 3) | ((k16 & 4) << 1) | ((k16 & 8) >> 1);  // swap bits2<->3
            Vf[fb + (s >> 6) * 4096 + (d >> 5) * 2048 + ((s >> 5) & 1) * 1024 +
               ((s >> 4) & 1) * 512 + (ks >> 3) * 256 + (d & 31) * 8 + (ks & 7)] = f2bf(v);
          }
        }
      }
}

// ---------------- pass 2: flash attention (round-12 structure, all-coalesced) ----------------
// 1 wave / block; swapped-operand in-register softmax. Q/K/V all fragment-native
// (coalesced 1KB wave-loads). V loads issued before the QK MFMAs (latency cover).
__global__ __launch_bounds__(64) void attn_kernel(char* __restrict__ ws) {
  const u16* QF = (const u16*)(ws + WS_QF);
  const u16* KF = (const u16*)(ws + WS_KF);
  const u16* VF = (const u16*)(ws + WS_VF);
  u16* ctx = (u16*)(ws + WS_CTX);

  const int l = threadIdx.x, l31 = l & 31, hi = l >> 5;

  // bijective XCD swizzle: 2048 blocks = 8 * 256; 4 heads' K/V per XCD (~2MB, L2-fits)
  const int id = blockIdx.y * 64 + blockIdx.x;
  const int sw = (id & 7) * 256 + (id >> 3);
  const int bh = sw >> 6, qt = sw & 63;

  const u16* Qp = QF + (size_t)bh * 131072u;
  const u16* Kp = KF + (size_t)bh * 131072u;
  const u16* Vp = VF + (size_t)bh * 131072u;
  const int q = qt * 32 + l31;

  bf16x8 qf[4];
#pragma unroll
  for (int kk = 0; kk < 4; ++kk)
    qf[kk] = __builtin_bit_cast(bf16x8, *(const u16x8*)(Qp + (qt * 4 + kk) * 512 + l * 8));

  f32x16 o0 = {}, o1 = {};
  float m = -1e30f, ls = 0.f;

  u16x8 ka[8], kb[8];
#pragma unroll
  for (int g = 0; g < 2; ++g)
#pragma unroll
    for (int kk = 0; kk < 4; ++kk)
      ka[g * 4 + kk] = *(const u16x8*)(Kp + (g * 4 + kk) * 512 + l * 8);

#define ATTN_BODY(KC, KN, T)                                                             \
  {                                                                                      \
    const int tn = ((T) + 1) & 31;                                                       \
    _Pragma("unroll")                                                                    \
    for (int g = 0; g < 2; ++g)                                                          \
      _Pragma("unroll")                                                                  \
      for (int kk = 0; kk < 4; ++kk)                                                     \
        KN[g * 4 + kk] = *(const u16x8*)(Kp + tn * 4096 + (g * 4 + kk) * 512 + l * 8);   \
    u16x8 vf[2][2][2]; /* [g32][dtile][kk16] — issued early, consumed after softmax */   \
    _Pragma("unroll")                                                                    \
    for (int g = 0; g < 2; ++g)                                                          \
      _Pragma("unroll")                                                                  \
      for (int dt = 0; dt < 2; ++dt)                                                     \
        _Pragma("unroll")                                                                \
        for (int kk = 0; kk < 2; ++kk)                                                   \
          vf[g][dt][kk] = *(const u16x8*)(Vp + (T) * 4096 +                              \
                                          (dt * 4 + g * 2 + kk) * 512 + l * 8);          \
    f32x16 s0 = {}, s1 = {};                                                             \
    __builtin_amdgcn_s_setprio(1);                                                       \
    _Pragma("unroll")                                                                    \
    for (int kk = 0; kk < 4; ++kk)                                                       \
      s0 = __builtin_amdgcn_mfma_f32_32x32x16_bf16(                                      \
          __builtin_bit_cast(bf16x8, KC[kk]), qf[kk], s0, 0, 0, 0);                      \
    _Pragma("unroll")                                                                    \
    for (int kk = 0; kk < 4; ++kk)                                                       \
      s1 = __builtin_amdgcn_mfma_f32_32x32x16_bf16(                                      \
          __builtin_bit_cast(bf16x8, KC[4 + kk]), qf[kk], s1, 0, 0, 0);                  \
    __builtin_amdgcn_s_setprio(0);                                                       \
    float pm[4] = {-1e30f, -1e30f, -1e30f, -1e30f};                                      \
    _Pragma("unroll")                                                                    \
    for (int r = 0; r < 16; ++r) {                                                       \
      pm[r & 3] = fmaxf(pm[r & 3], s0[r]);                                               \
      pm[r & 3] = fmaxf(pm[r & 3], s1[r]);                                               \
    }                                                                                    \
    float pmax = fmaxf(fmaxf(pm[0], pm[1]), fmaxf(pm[2], pm[3]));                        \
    pmax = fmaxf(pmax, __shfl_xor(pmax, 32));                                            \
    if (__any(pmax > m + 8.0f)) {                                                        \
      const float mn = fmaxf(m, pmax);                                                   \
      const float esc = __builtin_amdgcn_exp2f(m - mn);                                  \
      m = mn;                                                                            \
      ls *= esc;                                                                         \
      _Pragma("unroll")                                                                  \
      for (int r = 0; r < 16; ++r) { o0[r] *= esc; o1[r] *= esc; }                       \
    }                                                                                    \
    float p0[16], p1[16], sr[4] = {0.f, 0.f, 0.f, 0.f};                                  \
    _Pragma("unroll")                                                                    \
    for (int r = 0; r < 16; ++r) {                                                       \
      p0[r] = __builtin_amdgcn_exp2f(s0[r] - m);                                         \
      p1[r] = __builtin_amdgcn_exp2f(s1[r] - m);                                         \
      sr[r & 3] += p0[r] + p1[r];                                                        \
    }                                                                                    \
    float rs = (sr[0] + sr[1]) + (sr[2] + sr[3]);                                        \
    rs += __shfl_xor(rs, 32);                                                            \
    ls += rs;                                                                            \
    u32 pw[16];                                                                          \
    _Pragma("unroll")                                                                    \
    for (int t2 = 0; t2 < 8; ++t2) {                                                     \
      pw[t2] = cvtpk(p0[2 * t2], p0[2 * t2 + 1]);                                        \
      pw[8 + t2] = cvtpk(p1[2 * t2], p1[2 * t2 + 1]);                                    \
    }                                                                                    \
    __builtin_amdgcn_s_setprio(1);                                                       \
    _Pragma("unroll")                                                                    \
    for (int g = 0; g < 2; ++g)                                                          \
      _Pragma("unroll")                                                                  \
      for (int kk = 0; kk < 2; ++kk) {                                                   \
        u32x4 wv = {pw[g * 8 + kk * 4 + 0], pw[g * 8 + kk * 4 + 1],                      \
                    pw[g * 8 + kk * 4 + 2], pw[g * 8 + kk * 4 + 3]};                     \
        bf16x8 pf = __builtin_bit_cast(bf16x8, wv);                                      \
        o0 = __builtin_amdgcn_mfma_f32_32x32x16_bf16(                                    \
            __builtin_bit_cast(bf16x8, vf[g][0][kk]), pf, o0, 0, 0, 0);                  \
        o1 = __builtin_amdgcn_mfma_f32_32x32x16_bf16(                                    \
            __builtin_bit_cast(bf16x8, vf[g][1][kk]), pf, o1, 0, 0, 0);                  \
      }                                                                                  \
    __builtin_amdgcn_s_setprio(0);                                                       \
  }

  for (int tt = 0; tt < 16; ++tt) {
    ATTN_BODY(ka, kb, 2 * tt);
    ATTN_BODY(kb, ka, 2 * tt + 1);
  }
#undef ATTN_BODY

  const int bb = bh >> 4, hh = bh & 15;
  const float rl = 1.0f / ls;
  u16* cp = ctx + ((size_t)bb * SEQ + q) * EMBED + hh * 64;
#pragma unroll
  for (int rr = 0; rr < 4; ++rr) {
    u16x4 ov0, ov1;
#pragma unroll
    for (int j = 0; j < 4; ++j) {
      ov0[j] = f2bf(o0[rr * 4 + j] * rl);
      ov1[j] = f2bf(o1[rr * 4 + j] * rl);
    }
    *(u16x4*)(cp + rr * 8 + hi * 4) = ov0;
    *(u16x4*)(cp + 32 + rr * 8 + hi * 4) = ov1;
  }
}

extern "C" void kernel_launch(void* const* d_in, const int* in_sizes, int n_in,
                              void* d_out, int out_size, void* d_ws, size_t ws_size,
                              hipStream_t stream) {
  const float* q   = (const float*)d_in[0];
  const float* kin = (const float*)d_in[1];
  const float* val = (const float*)d_in[2];
  const float* Wq  = (const float*)d_in[3];
  const float* bq  = (const float*)d_in[4];
  const float* Wk  = (const float*)d_in[5];
  const float* bk  = (const float*)d_in[6];
  const float* Wv  = (const float*)d_in[7];
  const float* bv  = (const float*)d_in[8];
  const float* Wo  = (const float*)d_in[9];
  const float* bo  = (const float*)d_in[10];
  char* ws = (char*)d_ws;
  float* out = (float*)d_out;

  cvt_kernel<<<dim3(2048, 1, 3), 256, 0, stream>>>(q, kin, val, (u16*)(ws + WS_X));
  wtrans_kernel<<<dim3(32, 32, 4), dim3(32, 8), 0, stream>>>(Wq, Wk, Wv, Wo, (u16*)(ws + WS_WT));
  gemm128<0><<<dim3(8, 32, 3), 256, 0, stream>>>(ws, bq, bk, bv, nullptr);
  attn_kernel<<<dim3(64, 32), 64, 0, stream>>>(ws);
  gemm128<1><<<dim3(8, 32, 1), 256, 0, stream>>>(ws, bo, nullptr, nullptr, out);
}